// Round 1
// baseline (117.007 us; speedup 1.0000x reference)
//
#include <hip/hip_runtime.h>
#include <hip/hip_bf16.h>

typedef __attribute__((ext_vector_type(4))) float f32x4;
typedef __attribute__((ext_vector_type(8))) short s16x8;
typedef __attribute__((ext_vector_type(4))) float float4_t;

__device__ __forceinline__ ushort f2bf(float f) {
  union { float f; unsigned u; } v; v.f = f;
  unsigned r = v.u + 0x7fffu + ((v.u >> 16) & 1u);
  return (ushort)(r >> 16);
}

// ---------------- fused QKV projection GEMM ----------------
// C[s, n] = sum_k x[s,k] * W[n,k] + b[n]   (n in [0,3072) -> proj p = n>>10)
// Output: qkv[p][h][s][64] bf16, Q scaled by 1/8.
__global__ __launch_bounds__(256) void qkv_gemm_kernel(
    const float* __restrict__ x, const float* __restrict__ Wq,
    const float* __restrict__ Wk, const float* __restrict__ Wv,
    const float* __restrict__ bq, const float* __restrict__ bk,
    const float* __restrict__ bv, ushort* __restrict__ qkv) {
  __shared__ ushort lA[128 * 64];
  __shared__ ushort lB[128 * 64];
  const int t = threadIdx.x;
  const int lane = t & 63;
  const int w = t >> 6;
  const int wr = w >> 1, wc = w & 1;
  const int m0 = blockIdx.x * 128;
  const int n0 = blockIdx.y * 128;
  const int p = n0 >> 10;
  const float* __restrict__ W = (p == 0) ? Wq : (p == 1) ? Wk : Wv;
  const float* __restrict__ bias = (p == 0) ? bq : (p == 1) ? bk : bv;
  const int nW = n0 & 1023;
  const int l15 = lane & 15, l4 = lane >> 4;

  f32x4 acc[4][4];
#pragma unroll
  for (int i = 0; i < 4; i++)
#pragma unroll
    for (int j = 0; j < 4; j++) acc[i][j] = (f32x4)0.f;

  for (int k0 = 0; k0 < 1024; k0 += 64) {
    // stage A (x tile) and B (W tile), f32 -> bf16, XOR-swizzled LDS
#pragma unroll
    for (int i = 0; i < 4; i++) {
      int ch = t + i * 256;          // 0..1023
      int row = ch >> 3, c = ch & 7; // row 0..127, 8-elem chunk
      const float4_t* sA = (const float4_t*)&x[(size_t)(m0 + row) * 1024 + k0 + c * 8];
      float4_t a0 = sA[0], a1 = sA[1];
      s16x8 va;
      va[0] = (short)f2bf(a0[0]); va[1] = (short)f2bf(a0[1]);
      va[2] = (short)f2bf(a0[2]); va[3] = (short)f2bf(a0[3]);
      va[4] = (short)f2bf(a1[0]); va[5] = (short)f2bf(a1[1]);
      va[6] = (short)f2bf(a1[2]); va[7] = (short)f2bf(a1[3]);
      *(s16x8*)&lA[row * 64 + ((c ^ (row & 7)) * 8)] = va;
      const float4_t* sB = (const float4_t*)&W[(size_t)(nW + row) * 1024 + k0 + c * 8];
      float4_t b0 = sB[0], b1 = sB[1];
      s16x8 vb;
      vb[0] = (short)f2bf(b0[0]); vb[1] = (short)f2bf(b0[1]);
      vb[2] = (short)f2bf(b0[2]); vb[3] = (short)f2bf(b0[3]);
      vb[4] = (short)f2bf(b1[0]); vb[5] = (short)f2bf(b1[1]);
      vb[6] = (short)f2bf(b1[2]); vb[7] = (short)f2bf(b1[3]);
      *(s16x8*)&lB[row * 64 + ((c ^ (row & 7)) * 8)] = vb;
    }
    __syncthreads();
#pragma unroll
    for (int ks = 0; ks < 2; ks++) {
      s16x8 af[4], bfv[4];
#pragma unroll
      for (int i = 0; i < 4; i++) {
        int rowa = wr * 64 + i * 16 + l15;
        int ga = (ks * 4 + l4) ^ (rowa & 7);
        af[i] = *(const s16x8*)&lA[rowa * 64 + ga * 8];
        int rowb = wc * 64 + i * 16 + l15;
        int gb = (ks * 4 + l4) ^ (rowb & 7);
        bfv[i] = *(const s16x8*)&lB[rowb * 64 + gb * 8];
      }
#pragma unroll
      for (int mi = 0; mi < 4; mi++)
#pragma unroll
        for (int ni = 0; ni < 4; ni++)
          acc[mi][ni] = __builtin_amdgcn_mfma_f32_16x16x32_bf16(af[mi], bfv[ni], acc[mi][ni], 0, 0, 0);
    }
    __syncthreads();
  }
  // epilogue: bias, Q-scale, write bf16 to [p][h][s][64]
  const float qscale = (p == 0) ? 0.125f : 1.0f;
#pragma unroll
  for (int ni = 0; ni < 4; ni++) {
    int col = nW + wc * 64 + ni * 16 + l15;
    float b = bias[col];
    int h = col >> 6, dd = col & 63;
#pragma unroll
    for (int mi = 0; mi < 4; mi++) {
#pragma unroll
      for (int r = 0; r < 4; r++) {
        int s = m0 + wr * 64 + mi * 16 + l4 * 4 + r;
        float v = (acc[mi][ni][r] + b) * qscale;
        qkv[((size_t)(p * 16 + h) * 4096 + s) * 64 + dd] = f2bf(v);
      }
    }
  }
}

// ---------------- banded flash attention ----------------
// blocks: (qb 0..63, h 0..15); 4 waves x 16 Q-rows. Window |q-k| <= 256.
__global__ __launch_bounds__(256) void attn_local_kernel(
    const ushort* __restrict__ qkv, float* __restrict__ out) {
  __shared__ ushort lK[32 * 64];      // K tile, swizzled rows of 64
  __shared__ ushort lV[64 * 32];      // V^T tile, swizzled rows of 32
  __shared__ ushort lP[4 * 16 * 32];  // per-wave P buffer
  const int qb = blockIdx.x;
  const int h = blockIdx.y;
  const int q0 = qb * 64;
  const int t = threadIdx.x;
  const int lane = t & 63, w = t >> 6;
  const int l15 = lane & 15, l4 = lane >> 4;
  const int qw = q0 + w * 16;

  const ushort* __restrict__ Q = qkv;
  const ushort* __restrict__ K = qkv + (size_t)16 * 4096 * 64;
  const ushort* __restrict__ V = K + (size_t)16 * 4096 * 64;

  // Q fragments (A operand): row = l15, k = kc*32 + l4*8 + j
  s16x8 qf[2];
  {
    const ushort* qp = &Q[((size_t)h * 4096 + qw + l15) * 64];
    qf[0] = *(const s16x8*)&qp[l4 * 8];
    qf[1] = *(const s16x8*)&qp[32 + l4 * 8];
  }

  f32x4 oacc[4];
#pragma unroll
  for (int i = 0; i < 4; i++) oacc[i] = (f32x4)0.f;
  float mrow[4] = {-1e30f, -1e30f, -1e30f, -1e30f};
  float lrow[4] = {0.f, 0.f, 0.f, 0.f};

  int kstart = q0 - 256; if (kstart < 0) kstart = 0;
  int kend = q0 + 320; if (kend > 4096) kend = 4096;

  for (int kb = kstart; kb < kend; kb += 32) {
    {  // stage K [32][64] and V^T [64][32]
      int key = t >> 3, c = t & 7;
      s16x8 kv = *(const s16x8*)&K[((size_t)h * 4096 + kb + key) * 64 + c * 8];
      *(s16x8*)&lK[key * 64 + ((c ^ (key & 7)) * 8)] = kv;
      int dv = t & 63, kblk = t >> 6;
      const ushort* vb = &V[((size_t)h * 4096 + kb + kblk * 8) * 64 + dv];
      s16x8 vv;
#pragma unroll
      for (int j = 0; j < 8; j++) vv[j] = (short)vb[(size_t)j * 64];
      *(s16x8*)&lV[dv * 32 + ((kblk ^ (dv & 3)) * 8)] = vv;
    }
    __syncthreads();

    bool active = (kb + 31 >= qw - 256) && (kb <= qw + 15 + 256);
    if (active) {
      // S = Q K^T  (2 halves of 16 keys, K-dim 64 = 2 chunks)
      f32x4 sacc[2];
      sacc[0] = (f32x4)0.f; sacc[1] = (f32x4)0.f;
#pragma unroll
      for (int half = 0; half < 2; half++) {
#pragma unroll
        for (int kc = 0; kc < 2; kc++) {
          int krow = half * 16 + l15;
          int g = (kc * 4 + l4) ^ (krow & 7);
          s16x8 kf = *(const s16x8*)&lK[krow * 64 + g * 8];
          sacc[half] = __builtin_amdgcn_mfma_f32_16x16x32_bf16(qf[kc], kf, sacc[half], 0, 0, 0);
        }
      }
      // band mask + online softmax (rows = l4*4+r, keys = kb + half*16 + l15)
      float pv[2][4], scl[4];
#pragma unroll
      for (int r = 0; r < 4; r++) {
        int q = qw + l4 * 4 + r;
        int key0 = kb + l15;
        float s0 = ((unsigned)(q - key0 + 256) <= 512u) ? sacc[0][r] : -3e38f;
        float s1 = ((unsigned)(q - key0 - 16 + 256) <= 512u) ? sacc[1][r] : -3e38f;
        float rm = fmaxf(s0, s1);
        rm = fmaxf(rm, __shfl_xor(rm, 1));
        rm = fmaxf(rm, __shfl_xor(rm, 2));
        rm = fmaxf(rm, __shfl_xor(rm, 4));
        rm = fmaxf(rm, __shfl_xor(rm, 8));
        float mn = fmaxf(mrow[r], rm);
        float sc = __expf(mrow[r] - mn);
        float p0 = __expf(s0 - mn);
        float p1 = __expf(s1 - mn);
        float rs = p0 + p1;
        rs += __shfl_xor(rs, 1);
        rs += __shfl_xor(rs, 2);
        rs += __shfl_xor(rs, 4);
        rs += __shfl_xor(rs, 8);
        mrow[r] = mn;
        lrow[r] = lrow[r] * sc + rs;
        scl[r] = sc;
        pv[0][r] = p0; pv[1][r] = p1;
      }
      // P -> per-wave LDS (swizzled), re-fragment D-layout -> A-layout
      ushort* Pw = &lP[w * 512];
#pragma unroll
      for (int half = 0; half < 2; half++)
#pragma unroll
        for (int r = 0; r < 4; r++) {
          int rr = l4 * 4 + r;
          int col = half * 16 + l15;
          int g = (col >> 3) ^ (rr & 3);
          Pw[rr * 32 + g * 8 + (col & 7)] = f2bf(pv[half][r]);
        }
#pragma unroll
      for (int dvg = 0; dvg < 4; dvg++)
#pragma unroll
        for (int r = 0; r < 4; r++) oacc[dvg][r] *= scl[r];
      int gp = l4 ^ (l15 & 3);
      s16x8 pf = *(const s16x8*)&Pw[l15 * 32 + gp * 8];
#pragma unroll
      for (int dvg = 0; dvg < 4; dvg++) {
        int dv = dvg * 16 + l15;
        int gv = l4 ^ (dv & 3);
        s16x8 vf = *(const s16x8*)&lV[dv * 32 + gv * 8];
        oacc[dvg] = __builtin_amdgcn_mfma_f32_16x16x32_bf16(pf, vf, oacc[dvg], 0, 0, 0);
      }
    }
    __syncthreads();
  }
#pragma unroll
  for (int dvg = 0; dvg < 4; dvg++)
#pragma unroll
    for (int r = 0; r < 4; r++) {
      int s = qw + l4 * 4 + r;
      out[(size_t)s * 1024 + h * 64 + dvg * 16 + l15] = oacc[dvg][r] / lrow[r];
    }
}

extern "C" void kernel_launch(void* const* d_in, const int* in_sizes, int n_in,
                              void* d_out, int out_size, void* d_ws, size_t ws_size,
                              hipStream_t stream) {
  const float* x  = (const float*)d_in[0];
  const float* Wq = (const float*)d_in[1];
  const float* bq = (const float*)d_in[2];
  const float* Wk = (const float*)d_in[3];
  const float* bk = (const float*)d_in[4];
  const float* Wv = (const float*)d_in[5];
  const float* bv = (const float*)d_in[6];
  ushort* qkv = (ushort*)d_ws;   // [3][16][4096][64] bf16 = 24 MB
  float* out = (float*)d_out;

  qkv_gemm_kernel<<<dim3(32, 24), 256, 0, stream>>>(x, Wq, Wk, Wv, bq, bk, bv, qkv);
  attn_local_kernel<<<dim3(64, 16), 256, 0, stream>>>(qkv, out);
}

// Round 2
// 103.443 us; speedup vs baseline: 1.1311x; 1.1311x over previous
//
#include <hip/hip_runtime.h>
#include <hip/hip_bf16.h>

typedef __attribute__((ext_vector_type(4))) float f32x4;
typedef __attribute__((ext_vector_type(8))) short s16x8;
typedef __attribute__((ext_vector_type(4))) float float4_t;

__device__ __forceinline__ ushort f2bf(float f) {
  union { float f; unsigned u; } v; v.f = f;
  unsigned r = v.u + 0x7fffu + ((v.u >> 16) & 1u);
  return (ushort)(r >> 16);
}

__device__ __forceinline__ void async_copy16(ushort* lds, const ushort* g) {
  __builtin_amdgcn_global_load_lds(
      (const __attribute__((address_space(1))) unsigned int*)g,
      (__attribute__((address_space(3))) unsigned int*)lds, 16, 0, 0);
}

// ---------- f32 -> bf16 pre-swizzled panel conversion ----------
// Panels: [tile_r][tile_k][128 rows][64 cols], row r swizzled: chunk c8 stored
// at (c8 ^ (r&7)). Staged linearly by global_load_lds, read back with same XOR.
__global__ __launch_bounds__(256) void convert_x_kernel(
    const float* __restrict__ x, ushort* __restrict__ xs) {
  int c = blockIdx.x * 256 + threadIdx.x;  // 8-elem chunk id, 524288 total
  int kc = c & 127;                        // chunk within K=1024 row
  int m = c >> 7;
  const float4_t* s = (const float4_t*)&x[(size_t)m * 1024 + kc * 8];
  float4_t a0 = s[0], a1 = s[1];
  s16x8 v;
  v[0] = (short)f2bf(a0[0]); v[1] = (short)f2bf(a0[1]);
  v[2] = (short)f2bf(a0[2]); v[3] = (short)f2bf(a0[3]);
  v[4] = (short)f2bf(a1[0]); v[5] = (short)f2bf(a1[1]);
  v[6] = (short)f2bf(a1[2]); v[7] = (short)f2bf(a1[3]);
  int tm = m >> 7, tk = kc >> 3, r = m & 127, c8 = kc & 7;
  *(s16x8*)&xs[((size_t)(tm * 16 + tk) * 128 + r) * 64 + ((c8 ^ (r & 7)) * 8)] = v;
}

__global__ __launch_bounds__(256) void convert_w_kernel(
    const float* __restrict__ Wq, const float* __restrict__ Wk,
    const float* __restrict__ Wv, ushort* __restrict__ ws) {
  int c = blockIdx.x * 256 + threadIdx.x;  // 393216 total
  int kc = c & 127;
  int n = c >> 7;                           // 0..3071
  int p = n >> 10, nW = n & 1023;
  const float* __restrict__ W = (p == 0) ? Wq : (p == 1) ? Wk : Wv;
  const float4_t* s = (const float4_t*)&W[(size_t)nW * 1024 + kc * 8];
  float4_t a0 = s[0], a1 = s[1];
  s16x8 v;
  v[0] = (short)f2bf(a0[0]); v[1] = (short)f2bf(a0[1]);
  v[2] = (short)f2bf(a0[2]); v[3] = (short)f2bf(a0[3]);
  v[4] = (short)f2bf(a1[0]); v[5] = (short)f2bf(a1[1]);
  v[6] = (short)f2bf(a1[2]); v[7] = (short)f2bf(a1[3]);
  int tn = n >> 7, tk = kc >> 3, r = n & 127, c8 = kc & 7;
  *(s16x8*)&ws[((size_t)(tn * 16 + tk) * 128 + r) * 64 + ((c8 ^ (r & 7)) * 8)] = v;
}

// ---------------- fused QKV projection GEMM (m97 structure) ----------------
// C[s, n] = sum_k x[s,k] * W[n,k] + b[n]; output qkv[p][h][s][64] bf16, Q scaled 1/8.
__global__ __launch_bounds__(256) void qkv_gemm_kernel(
    const ushort* __restrict__ xs, const ushort* __restrict__ ws,
    const float* __restrict__ bq, const float* __restrict__ bk,
    const float* __restrict__ bv, ushort* __restrict__ qkv) {
  __shared__ ushort lA[8192];
  __shared__ ushort lB[8192];
  const int t = threadIdx.x;
  const int lane = t & 63, w = t >> 6;
  const int wr = w >> 1, wc = w & 1;
  const int l15 = lane & 15, l4 = lane >> 4;
  const int bm = blockIdx.x, bn = blockIdx.y;

  f32x4 acc[4][4];
#pragma unroll
  for (int i = 0; i < 4; i++)
#pragma unroll
    for (int j = 0; j < 4; j++) acc[i][j] = (f32x4)0.f;

  const ushort* Abase = xs + (size_t)bm * 16 * 8192;
  const ushort* Bbase = ws + (size_t)bn * 16 * 8192;

  for (int kt = 0; kt < 16; ++kt) {
    const ushort* ga = Abase + kt * 8192;
    const ushort* gb = Bbase + kt * 8192;
#pragma unroll
    for (int i = 0; i < 4; i++) {
      int chunk = i * 4 + w;  // 0..15, 512 ushorts (1 KB) each
      async_copy16(&lA[chunk * 512 + lane * 8], ga + chunk * 512 + lane * 8);
      async_copy16(&lB[chunk * 512 + lane * 8], gb + chunk * 512 + lane * 8);
    }
    __syncthreads();
#pragma unroll
    for (int ks = 0; ks < 2; ks++) {
      s16x8 af[4], bfv[4];
#pragma unroll
      for (int i = 0; i < 4; i++) {
        int rowa = wr * 64 + i * 16 + l15;
        int gca = (ks * 4 + l4) ^ (rowa & 7);
        af[i] = *(const s16x8*)&lA[rowa * 64 + gca * 8];
        int rowb = wc * 64 + i * 16 + l15;
        int gcb = (ks * 4 + l4) ^ (rowb & 7);
        bfv[i] = *(const s16x8*)&lB[rowb * 64 + gcb * 8];
      }
#pragma unroll
      for (int mi = 0; mi < 4; mi++)
#pragma unroll
        for (int ni = 0; ni < 4; ni++)
          acc[mi][ni] = __builtin_amdgcn_mfma_f32_16x16x32_bf16(af[mi], bfv[ni], acc[mi][ni], 0, 0, 0);
    }
    __syncthreads();
  }

  const int n0 = bn * 128;
  const int p = n0 >> 10;
  const int nW = n0 & 1023;
  const float* __restrict__ bias = (p == 0) ? bq : (p == 1) ? bk : bv;
  const float qscale = (p == 0) ? 0.125f : 1.0f;
#pragma unroll
  for (int ni = 0; ni < 4; ni++) {
    int col = nW + wc * 64 + ni * 16 + l15;
    float b = bias[col];
    int h = col >> 6, dd = col & 63;
#pragma unroll
    for (int mi = 0; mi < 4; mi++) {
#pragma unroll
      for (int r = 0; r < 4; r++) {
        int s = bm * 128 + wr * 64 + mi * 16 + l4 * 4 + r;
        float v = (acc[mi][ni][r] + b) * qscale;
        qkv[((size_t)(p * 16 + h) * 4096 + s) * 64 + dd] = f2bf(v);
      }
    }
  }
}

// ---------------- banded flash attention ----------------
__global__ __launch_bounds__(256) void attn_local_kernel(
    const ushort* __restrict__ qkv, float* __restrict__ out) {
  __shared__ ushort lK[32 * 64];
  __shared__ ushort lV[64 * 32];
  __shared__ ushort lP[4 * 16 * 32];
  const int qb = blockIdx.x;
  const int h = blockIdx.y;
  const int q0 = qb * 64;
  const int t = threadIdx.x;
  const int lane = t & 63, w = t >> 6;
  const int l15 = lane & 15, l4 = lane >> 4;
  const int qw = q0 + w * 16;

  const ushort* __restrict__ Q = qkv;
  const ushort* __restrict__ K = qkv + (size_t)16 * 4096 * 64;
  const ushort* __restrict__ V = K + (size_t)16 * 4096 * 64;

  s16x8 qf[2];
  {
    const ushort* qp = &Q[((size_t)h * 4096 + qw + l15) * 64];
    qf[0] = *(const s16x8*)&qp[l4 * 8];
    qf[1] = *(const s16x8*)&qp[32 + l4 * 8];
  }

  f32x4 oacc[4];
#pragma unroll
  for (int i = 0; i < 4; i++) oacc[i] = (f32x4)0.f;
  float mrow[4] = {-1e30f, -1e30f, -1e30f, -1e30f};
  float lrow[4] = {0.f, 0.f, 0.f, 0.f};

  int kstart = q0 - 256; if (kstart < 0) kstart = 0;
  int kend = q0 + 320; if (kend > 4096) kend = 4096;

  for (int kb = kstart; kb < kend; kb += 32) {
    {
      int key = t >> 3, c = t & 7;
      s16x8 kv = *(const s16x8*)&K[((size_t)h * 4096 + kb + key) * 64 + c * 8];
      *(s16x8*)&lK[key * 64 + ((c ^ (key & 7)) * 8)] = kv;
      int dv = t & 63, kblk = t >> 6;
      const ushort* vb = &V[((size_t)h * 4096 + kb + kblk * 8) * 64 + dv];
      s16x8 vv;
#pragma unroll
      for (int j = 0; j < 8; j++) vv[j] = (short)vb[(size_t)j * 64];
      *(s16x8*)&lV[dv * 32 + ((kblk ^ (dv & 3)) * 8)] = vv;
    }
    __syncthreads();

    bool active = (kb + 31 >= qw - 256) && (kb <= qw + 15 + 256);
    if (active) {
      f32x4 sacc[2];
      sacc[0] = (f32x4)0.f; sacc[1] = (f32x4)0.f;
#pragma unroll
      for (int half = 0; half < 2; half++) {
#pragma unroll
        for (int kc = 0; kc < 2; kc++) {
          int krow = half * 16 + l15;
          int g = (kc * 4 + l4) ^ (krow & 7);
          s16x8 kf = *(const s16x8*)&lK[krow * 64 + g * 8];
          sacc[half] = __builtin_amdgcn_mfma_f32_16x16x32_bf16(qf[kc], kf, sacc[half], 0, 0, 0);
        }
      }
      float pv[2][4], scl[4];
#pragma unroll
      for (int r = 0; r < 4; r++) {
        int q = qw + l4 * 4 + r;
        int key0 = kb + l15;
        float s0 = ((unsigned)(q - key0 + 256) <= 512u) ? sacc[0][r] : -3e38f;
        float s1 = ((unsigned)(q - key0 - 16 + 256) <= 512u) ? sacc[1][r] : -3e38f;
        float rm = fmaxf(s0, s1);
        rm = fmaxf(rm, __shfl_xor(rm, 1));
        rm = fmaxf(rm, __shfl_xor(rm, 2));
        rm = fmaxf(rm, __shfl_xor(rm, 4));
        rm = fmaxf(rm, __shfl_xor(rm, 8));
        float mn = fmaxf(mrow[r], rm);
        float sc = __expf(mrow[r] - mn);
        float p0 = __expf(s0 - mn);
        float p1 = __expf(s1 - mn);
        float rs = p0 + p1;
        rs += __shfl_xor(rs, 1);
        rs += __shfl_xor(rs, 2);
        rs += __shfl_xor(rs, 4);
        rs += __shfl_xor(rs, 8);
        mrow[r] = mn;
        lrow[r] = lrow[r] * sc + rs;
        scl[r] = sc;
        pv[0][r] = p0; pv[1][r] = p1;
      }
      ushort* Pw = &lP[w * 512];
#pragma unroll
      for (int half = 0; half < 2; half++)
#pragma unroll
        for (int r = 0; r < 4; r++) {
          int rr = l4 * 4 + r;
          int col = half * 16 + l15;
          int g = (col >> 3) ^ (rr & 3);
          Pw[rr * 32 + g * 8 + (col & 7)] = f2bf(pv[half][r]);
        }
#pragma unroll
      for (int dvg = 0; dvg < 4; dvg++)
#pragma unroll
        for (int r = 0; r < 4; r++) oacc[dvg][r] *= scl[r];
      int gp = l4 ^ (l15 & 3);
      s16x8 pf = *(const s16x8*)&Pw[l15 * 32 + gp * 8];
#pragma unroll
      for (int dvg = 0; dvg < 4; dvg++) {
        int dv = dvg * 16 + l15;
        int gv = l4 ^ (dv & 3);
        s16x8 vf = *(const s16x8*)&lV[dv * 32 + gv * 8];
        oacc[dvg] = __builtin_amdgcn_mfma_f32_16x16x32_bf16(pf, vf, oacc[dvg], 0, 0, 0);
      }
    }
    __syncthreads();
  }
#pragma unroll
  for (int dvg = 0; dvg < 4; dvg++)
#pragma unroll
    for (int r = 0; r < 4; r++) {
      int s = qw + l4 * 4 + r;
      out[(size_t)s * 1024 + h * 64 + dvg * 16 + l15] = oacc[dvg][r] / lrow[r];
    }
}

extern "C" void kernel_launch(void* const* d_in, const int* in_sizes, int n_in,
                              void* d_out, int out_size, void* d_ws, size_t ws_size,
                              hipStream_t stream) {
  const float* x  = (const float*)d_in[0];
  const float* Wq = (const float*)d_in[1];
  const float* bq = (const float*)d_in[2];
  const float* Wk = (const float*)d_in[3];
  const float* bk = (const float*)d_in[4];
  const float* Wv = (const float*)d_in[5];
  const float* bv = (const float*)d_in[6];

  ushort* qkv = (ushort*)d_ws;                                   // 24 MB: [3][16][4096][64]
  ushort* xs  = (ushort*)((char*)d_ws + (size_t)25165824);       // 8 MB: x panels
  ushort* wsb = xs + (size_t)4096 * 1024;                        // 6 MB: W panels
  float* out = (float*)d_out;

  convert_x_kernel<<<2048, 256, 0, stream>>>(x, xs);
  convert_w_kernel<<<1536, 256, 0, stream>>>(Wq, Wk, Wv, wsb);
  qkv_gemm_kernel<<<dim3(32, 24), 256, 0, stream>>>(xs, wsb, bq, bk, bv, qkv);
  attn_local_kernel<<<dim3(64, 16), 256, 0, stream>>>(qkv, out);
}

// Round 3
// 86.579 us; speedup vs baseline: 1.3514x; 1.1948x over previous
//
#include <hip/hip_runtime.h>
#include <hip/hip_bf16.h>

typedef __attribute__((ext_vector_type(4))) float f32x4;
typedef __attribute__((ext_vector_type(8))) short s16x8;
typedef __attribute__((ext_vector_type(4))) float float4_t;
typedef __attribute__((ext_vector_type(2))) unsigned int u32x2;

union U8 { s16x8 v; unsigned u[4]; };

__device__ __forceinline__ ushort f2bf(float f) {
  union { float f; unsigned u; } v; v.f = f;
  unsigned r = v.u + 0x7fffu + ((v.u >> 16) & 1u);
  return (ushort)(r >> 16);
}

__device__ __forceinline__ void async_copy16(ushort* lds, const ushort* g) {
  __builtin_amdgcn_global_load_lds(
      (const __attribute__((address_space(1))) unsigned int*)g,
      (__attribute__((address_space(3))) unsigned int*)lds, 16, 0, 0);
}

__device__ __forceinline__ unsigned lds_addr(const void* p) {
  return (unsigned)(unsigned long long)(__attribute__((address_space(3))) const void*)p;
}

#define TRRD(dst, addr, off_lit) \
  asm volatile("ds_read_b64_tr_b16 %0, %1 offset:" #off_lit : "=v"(dst) : "v"(addr))

// ---------- f32 -> bf16 pre-swizzled panel conversion ----------
__global__ __launch_bounds__(256) void convert_x_kernel(
    const float* __restrict__ x, ushort* __restrict__ xs) {
  int c = blockIdx.x * 256 + threadIdx.x;
  int kc = c & 127;
  int m = c >> 7;
  const float4_t* s = (const float4_t*)&x[(size_t)m * 1024 + kc * 8];
  float4_t a0 = s[0], a1 = s[1];
  s16x8 v;
  v[0] = (short)f2bf(a0[0]); v[1] = (short)f2bf(a0[1]);
  v[2] = (short)f2bf(a0[2]); v[3] = (short)f2bf(a0[3]);
  v[4] = (short)f2bf(a1[0]); v[5] = (short)f2bf(a1[1]);
  v[6] = (short)f2bf(a1[2]); v[7] = (short)f2bf(a1[3]);
  int tm = m >> 7, tk = kc >> 3, r = m & 127, c8 = kc & 7;
  *(s16x8*)&xs[((size_t)(tm * 16 + tk) * 128 + r) * 64 + ((c8 ^ (r & 7)) * 8)] = v;
}

__global__ __launch_bounds__(256) void convert_w_kernel(
    const float* __restrict__ Wq, const float* __restrict__ Wk,
    const float* __restrict__ Wv, ushort* __restrict__ ws) {
  int c = blockIdx.x * 256 + threadIdx.x;
  int kc = c & 127;
  int n = c >> 7;
  int p = n >> 10, nW = n & 1023;
  const float* __restrict__ W = (p == 0) ? Wq : (p == 1) ? Wk : Wv;
  const float4_t* s = (const float4_t*)&W[(size_t)nW * 1024 + kc * 8];
  float4_t a0 = s[0], a1 = s[1];
  s16x8 v;
  v[0] = (short)f2bf(a0[0]); v[1] = (short)f2bf(a0[1]);
  v[2] = (short)f2bf(a0[2]); v[3] = (short)f2bf(a0[3]);
  v[4] = (short)f2bf(a1[0]); v[5] = (short)f2bf(a1[1]);
  v[6] = (short)f2bf(a1[2]); v[7] = (short)f2bf(a1[3]);
  int tn = n >> 7, tk = kc >> 3, r = n & 127, c8 = kc & 7;
  *(s16x8*)&ws[((size_t)(tn * 16 + tk) * 128 + r) * 64 + ((c8 ^ (r & 7)) * 8)] = v;
}

// ---------------- fused QKV projection GEMM (m97 structure) ----------------
__global__ __launch_bounds__(256) void qkv_gemm_kernel(
    const ushort* __restrict__ xs, const ushort* __restrict__ ws,
    const float* __restrict__ bq, const float* __restrict__ bk,
    const float* __restrict__ bv, ushort* __restrict__ qkv) {
  __shared__ ushort lA[8192];
  __shared__ ushort lB[8192];
  const int t = threadIdx.x;
  const int lane = t & 63, w = t >> 6;
  const int wr = w >> 1, wc = w & 1;
  const int l15 = lane & 15, l4 = lane >> 4;
  const int bm = blockIdx.x, bn = blockIdx.y;

  f32x4 acc[4][4];
#pragma unroll
  for (int i = 0; i < 4; i++)
#pragma unroll
    for (int j = 0; j < 4; j++) acc[i][j] = (f32x4)0.f;

  const ushort* Abase = xs + (size_t)bm * 16 * 8192;
  const ushort* Bbase = ws + (size_t)bn * 16 * 8192;

  for (int kt = 0; kt < 16; ++kt) {
    const ushort* ga = Abase + kt * 8192;
    const ushort* gb = Bbase + kt * 8192;
#pragma unroll
    for (int i = 0; i < 4; i++) {
      int chunk = i * 4 + w;
      async_copy16(&lA[chunk * 512 + lane * 8], ga + chunk * 512 + lane * 8);
      async_copy16(&lB[chunk * 512 + lane * 8], gb + chunk * 512 + lane * 8);
    }
    __syncthreads();
#pragma unroll
    for (int ks = 0; ks < 2; ks++) {
      s16x8 af[4], bfv[4];
#pragma unroll
      for (int i = 0; i < 4; i++) {
        int rowa = wr * 64 + i * 16 + l15;
        int gca = (ks * 4 + l4) ^ (rowa & 7);
        af[i] = *(const s16x8*)&lA[rowa * 64 + gca * 8];
        int rowb = wc * 64 + i * 16 + l15;
        int gcb = (ks * 4 + l4) ^ (rowb & 7);
        bfv[i] = *(const s16x8*)&lB[rowb * 64 + gcb * 8];
      }
#pragma unroll
      for (int mi = 0; mi < 4; mi++)
#pragma unroll
        for (int ni = 0; ni < 4; ni++)
          acc[mi][ni] = __builtin_amdgcn_mfma_f32_16x16x32_bf16(af[mi], bfv[ni], acc[mi][ni], 0, 0, 0);
    }
    __syncthreads();
  }

  const int n0 = bn * 128;
  const int p = n0 >> 10;
  const int nW = n0 & 1023;
  const float* __restrict__ bias = (p == 0) ? bq : (p == 1) ? bk : bv;
  const float qscale = (p == 0) ? 0.125f : 1.0f;
#pragma unroll
  for (int ni = 0; ni < 4; ni++) {
    int col = nW + wc * 64 + ni * 16 + l15;
    float b = bias[col];
    int h = col >> 6, dd = col & 63;
#pragma unroll
    for (int mi = 0; mi < 4; mi++) {
#pragma unroll
      for (int r = 0; r < 4; r++) {
        int s = bm * 128 + wr * 64 + mi * 16 + l4 * 4 + r;
        float v = (acc[mi][ni][r] + b) * qscale;
        qkv[((size_t)(p * 16 + h) * 4096 + s) * 64 + dd] = f2bf(v);
      }
    }
  }
}

// ---------------- banded flash attention (swapped QK^T, KT=64) ----------------
__global__ __launch_bounds__(256) void attn_local_kernel(
    const ushort* __restrict__ qkv, float* __restrict__ out) {
  __shared__ ushort lK[4096];  // [64 keys][64 d], row chunks XOR-swizzled
  __shared__ ushort lV[4096];  // [64 keys][64 d], natural layout (tr-read)
  const int bid = blockIdx.x;
  const int wid = (bid & 7) * 128 + (bid >> 3);   // XCD swizzle: 2 heads per XCD
  const int h = wid >> 6;
  const int q0 = (wid & 63) * 64;
  const int t = threadIdx.x;
  const int lane = t & 63, w = t >> 6;
  const int l15 = lane & 15, l4 = lane >> 4;
  const int qw = q0 + w * 16;
  const int myq = qw + l15;   // this lane's q row (S^T col)

  const ushort* __restrict__ Q = qkv;
  const ushort* __restrict__ K = qkv + (size_t)16 * 4096 * 64;
  const ushort* __restrict__ V = K + (size_t)16 * 4096 * 64;

  // Q as B-operand: col=l15 -> q, k-elems = kc*32 + l4*8 + j
  s16x8 qf[2];
  {
    const ushort* qp = &Q[((size_t)h * 4096 + myq) * 64];
    qf[0] = *(const s16x8*)&qp[l4 * 8];
    qf[1] = *(const s16x8*)&qp[32 + l4 * 8];
  }

  f32x4 oacc[4];   // db 0..3: rows q = qw + l4*4 + r, col d = db*16 + l15
#pragma unroll
  for (int i = 0; i < 4; i++) oacc[i] = (f32x4)0.f;
  float mrow = -1e30f, lrow = 0.f;

  // tr-read per-lane base: lane p of group l4 points at V[4*l4 + (p>>2)][4*(p&3)]
  const unsigned vtr = lds_addr(lV) +
      (unsigned)(l4 * 1024 + (l15 >> 2) * 128 + (l15 & 3) * 8);

  int kstart = q0 - 256; if (kstart < 0) kstart = 0;
  int kend = q0 + 320; if (kend > 4096) kend = 4096;

  for (int kb = kstart; kb < kend; kb += 64) {
    const ushort* Kg = &K[((size_t)h * 4096 + kb) * 64];
    const ushort* Vg = &V[((size_t)h * 4096 + kb) * 64];
#pragma unroll
    for (int i = 0; i < 2; i++) {
      int off = i * 2048 + t * 8;        // linear LDS ushort offset
      int row = off >> 6;
      int c8 = (off >> 3) & 7;
      async_copy16(&lK[off], &Kg[row * 64 + ((c8 ^ (row & 7)) * 8)]);
      async_copy16(&lV[off], &Vg[off]);
    }
    __syncthreads();

    bool active = (kb + 63 >= qw - 256) && (kb <= qw + 15 + 256);
    if (active) {
      // S^T = K x Q^T : rows=keys, cols=q
      f32x4 st[4];
#pragma unroll
      for (int tt = 0; tt < 4; tt++) st[tt] = (f32x4)0.f;
#pragma unroll
      for (int tt = 0; tt < 4; tt++) {
#pragma unroll
        for (int kc = 0; kc < 2; kc++) {
          int rowk = tt * 16 + l15;
          int g = (kc * 4 + l4) ^ (rowk & 7);
          s16x8 kf = *(const s16x8*)&lK[rowk * 64 + g * 8];
          st[tt] = __builtin_amdgcn_mfma_f32_16x16x32_bf16(kf, qf[kc], st[tt], 0, 0, 0);
        }
      }
      // mask + in-lane online softmax (lane owns q=myq, 16 k-values)
      float pe[4][4];
      float rm = -3e38f;
#pragma unroll
      for (int tt = 0; tt < 4; tt++)
#pragma unroll
        for (int r = 0; r < 4; r++) {
          int key = kb + tt * 16 + l4 * 4 + r;
          float s = ((unsigned)(myq - key + 256) <= 512u) ? st[tt][r] : -3e38f;
          pe[tt][r] = s;
          rm = fmaxf(rm, s);
        }
      rm = fmaxf(rm, __shfl_xor(rm, 16));
      rm = fmaxf(rm, __shfl_xor(rm, 32));
      float mn = fmaxf(mrow, rm);
      float sc = __expf(mrow - mn);
      float rs = 0.f;
#pragma unroll
      for (int tt = 0; tt < 4; tt++)
#pragma unroll
        for (int r = 0; r < 4; r++) {
          float e = __expf(pe[tt][r] - mn);
          pe[tt][r] = e;
          rs += e;
        }
      rs += __shfl_xor(rs, 16);
      rs += __shfl_xor(rs, 32);
      mrow = mn;
      lrow = lrow * sc + rs;
      // pack P to bf16 pairs: pk[tile][word]
      unsigned pk[4][2];
#pragma unroll
      for (int tt = 0; tt < 4; tt++) {
        asm("v_cvt_pk_bf16_f32 %0, %1, %2" : "=v"(pk[tt][0]) : "v"(pe[tt][0]), "v"(pe[tt][1]));
        asm("v_cvt_pk_bf16_f32 %0, %1, %2" : "=v"(pk[tt][1]) : "v"(pe[tt][2]), "v"(pe[tt][3]));
      }
      // rescale O rows (q = qw + l4*4 + r); sc uniform across l4 for same l15
      float scr[4];
#pragma unroll
      for (int r = 0; r < 4; r++) scr[r] = __shfl(sc, l4 * 4 + r);
#pragma unroll
      for (int db = 0; db < 4; db++)
#pragma unroll
        for (int r = 0; r < 4; r++) oacc[db][r] *= scr[r];

      // PV: 2 k-chunks of 32
#pragma unroll
      for (int c = 0; c < 2; c++) {
        u32x2 t00, t01, t10, t11, t20, t21, t30, t31;
        if (c == 0) {
          TRRD(t00, vtr, 0);    TRRD(t01, vtr, 512);
          TRRD(t10, vtr, 32);   TRRD(t11, vtr, 544);
          TRRD(t20, vtr, 64);   TRRD(t21, vtr, 576);
          TRRD(t30, vtr, 96);   TRRD(t31, vtr, 608);
        } else {
          TRRD(t00, vtr, 4096); TRRD(t01, vtr, 4608);
          TRRD(t10, vtr, 4128); TRRD(t11, vtr, 4640);
          TRRD(t20, vtr, 4160); TRRD(t21, vtr, 4672);
          TRRD(t30, vtr, 4192); TRRD(t31, vtr, 4704);
        }
        // redistribute P across l4 groups -> A-operand fragment
        const int srcA = ((lane & 16) << 1) | l15;
        const int srcB = srcA + 16;
        const int tsel = (lane >> 5) & 1;
        unsigned x0 = (unsigned)__shfl((int)pk[2 * c][0], srcA);
        unsigned y0 = (unsigned)__shfl((int)pk[2 * c + 1][0], srcA);
        unsigned x1 = (unsigned)__shfl((int)pk[2 * c][1], srcA);
        unsigned y1 = (unsigned)__shfl((int)pk[2 * c + 1][1], srcA);
        unsigned x2 = (unsigned)__shfl((int)pk[2 * c][0], srcB);
        unsigned y2 = (unsigned)__shfl((int)pk[2 * c + 1][0], srcB);
        unsigned x3 = (unsigned)__shfl((int)pk[2 * c][1], srcB);
        unsigned y3 = (unsigned)__shfl((int)pk[2 * c + 1][1], srcB);
        U8 pf;
        pf.u[0] = tsel ? y0 : x0;
        pf.u[1] = tsel ? y1 : x1;
        pf.u[2] = tsel ? y2 : x2;
        pf.u[3] = tsel ? y3 : x3;
        asm volatile("s_waitcnt lgkmcnt(0)");
        __builtin_amdgcn_sched_barrier(0);
        U8 vf0, vf1, vf2, vf3;
        vf0.u[0] = t00[0]; vf0.u[1] = t00[1]; vf0.u[2] = t01[0]; vf0.u[3] = t01[1];
        vf1.u[0] = t10[0]; vf1.u[1] = t10[1]; vf1.u[2] = t11[0]; vf1.u[3] = t11[1];
        vf2.u[0] = t20[0]; vf2.u[1] = t20[1]; vf2.u[2] = t21[0]; vf2.u[3] = t21[1];
        vf3.u[0] = t30[0]; vf3.u[1] = t30[1]; vf3.u[2] = t31[0]; vf3.u[3] = t31[1];
        oacc[0] = __builtin_amdgcn_mfma_f32_16x16x32_bf16(pf.v, vf0.v, oacc[0], 0, 0, 0);
        oacc[1] = __builtin_amdgcn_mfma_f32_16x16x32_bf16(pf.v, vf1.v, oacc[1], 0, 0, 0);
        oacc[2] = __builtin_amdgcn_mfma_f32_16x16x32_bf16(pf.v, vf2.v, oacc[2], 0, 0, 0);
        oacc[3] = __builtin_amdgcn_mfma_f32_16x16x32_bf16(pf.v, vf3.v, oacc[3], 0, 0, 0);
      }
    }
    __syncthreads();
  }
  // epilogue: divide by l (per q-row) and store f32
  float linv[4];
#pragma unroll
  for (int r = 0; r < 4; r++) linv[r] = 1.0f / __shfl(lrow, l4 * 4 + r);
#pragma unroll
  for (int db = 0; db < 4; db++)
#pragma unroll
    for (int r = 0; r < 4; r++) {
      int s = qw + l4 * 4 + r;
      out[(size_t)s * 1024 + h * 64 + db * 16 + l15] = oacc[db][r] * linv[r];
    }
}

extern "C" void kernel_launch(void* const* d_in, const int* in_sizes, int n_in,
                              void* d_out, int out_size, void* d_ws, size_t ws_size,
                              hipStream_t stream) {
  const float* x  = (const float*)d_in[0];
  const float* Wq = (const float*)d_in[1];
  const float* bq = (const float*)d_in[2];
  const float* Wk = (const float*)d_in[3];
  const float* bk = (const float*)d_in[4];
  const float* Wv = (const float*)d_in[5];
  const float* bv = (const float*)d_in[6];

  ushort* qkv = (ushort*)d_ws;                                   // 24 MB
  ushort* xs  = (ushort*)((char*)d_ws + (size_t)25165824);       // 8 MB
  ushort* wsb = xs + (size_t)4096 * 1024;                        // 6 MB
  float* out = (float*)d_out;

  convert_x_kernel<<<2048, 256, 0, stream>>>(x, xs);
  convert_w_kernel<<<1536, 256, 0, stream>>>(Wq, Wk, Wv, wsb);
  qkv_gemm_kernel<<<dim3(32, 24), 256, 0, stream>>>(xs, wsb, bq, bk, bv, qkv);
  attn_local_kernel<<<1024, 256, 0, stream>>>(qkv, out);
}

// Round 5
// 74.862 us; speedup vs baseline: 1.5630x; 1.1565x over previous
//
#include <hip/hip_runtime.h>
#include <hip/hip_bf16.h>

typedef __attribute__((ext_vector_type(4))) float f32x4;
typedef __attribute__((ext_vector_type(8))) short s16x8;
typedef __attribute__((ext_vector_type(4))) float float4_t;
typedef __attribute__((ext_vector_type(2))) unsigned int u32x2;

union U8 { s16x8 v; unsigned u[4]; };

__device__ __forceinline__ ushort f2bf(float f) {
  union { float f; unsigned u; } v; v.f = f;
  unsigned r = v.u + 0x7fffu + ((v.u >> 16) & 1u);
  return (ushort)(r >> 16);
}

__device__ __forceinline__ void async_copy16(ushort* lds, const ushort* g) {
  __builtin_amdgcn_global_load_lds(
      (const __attribute__((address_space(1))) unsigned int*)g,
      (__attribute__((address_space(3))) unsigned int*)lds, 16, 0, 0);
}

__device__ __forceinline__ unsigned lds_addr(const void* p) {
  return (unsigned)(unsigned long long)(__attribute__((address_space(3))) const void*)p;
}

#define TRRD(dst, addr, off_lit) \
  asm volatile("ds_read_b64_tr_b16 %0, %1 offset:" #off_lit : "=v"(dst) : "v"(addr))

// ---------- f32 -> bf16 pre-swizzled panel conversion ----------
// x panels: [tm 32][tk 16][128][64], row r chunk c8 stored at (c8 ^ (r&7)).
__global__ __launch_bounds__(256) void convert_x_kernel(
    const float* __restrict__ x, ushort* __restrict__ xs) {
  int c = blockIdx.x * 256 + threadIdx.x;
  int kc = c & 127;
  int m = c >> 7;
  const float4_t* s = (const float4_t*)&x[(size_t)m * 1024 + kc * 8];
  float4_t a0 = s[0], a1 = s[1];
  s16x8 v;
  v[0] = (short)f2bf(a0[0]); v[1] = (short)f2bf(a0[1]);
  v[2] = (short)f2bf(a0[2]); v[3] = (short)f2bf(a0[3]);
  v[4] = (short)f2bf(a1[0]); v[5] = (short)f2bf(a1[1]);
  v[6] = (short)f2bf(a1[2]); v[7] = (short)f2bf(a1[3]);
  int tm = m >> 7, tk = kc >> 3, r = m & 127, c8 = kc & 7;
  *(s16x8*)&xs[((size_t)(tm * 16 + tk) * 128 + r) * 64 + ((c8 ^ (r & 7)) * 8)] = v;
}

// W panels: [tn3 16][tk 16][192][64], same per-row XOR swizzle.
__global__ __launch_bounds__(256) void convert_w_kernel(
    const float* __restrict__ Wq, const float* __restrict__ Wk,
    const float* __restrict__ Wv, ushort* __restrict__ ws) {
  int c = blockIdx.x * 256 + threadIdx.x;
  int kc = c & 127;
  int n = c >> 7;
  int p = n >> 10, nW = n & 1023;
  const float* __restrict__ W = (p == 0) ? Wq : (p == 1) ? Wk : Wv;
  const float4_t* s = (const float4_t*)&W[(size_t)nW * 1024 + kc * 8];
  float4_t a0 = s[0], a1 = s[1];
  s16x8 v;
  v[0] = (short)f2bf(a0[0]); v[1] = (short)f2bf(a0[1]);
  v[2] = (short)f2bf(a0[2]); v[3] = (short)f2bf(a0[3]);
  v[4] = (short)f2bf(a1[0]); v[5] = (short)f2bf(a1[1]);
  v[6] = (short)f2bf(a1[2]); v[7] = (short)f2bf(a1[3]);
  unsigned tn3 = (unsigned)n / 192u;
  unsigned r = (unsigned)n - tn3 * 192u;
  int tk = kc >> 3, c8 = kc & 7;
  *(s16x8*)&ws[((size_t)(tn3 * 16 + tk) * 192 + r) * 64 + ((c8 ^ (r & 7)) * 8)] = v;
}

// ---------------- fused QKV GEMM: 256x192 tile, BK=64, 8 waves, dbuf pipeline ----
__global__ __launch_bounds__(512, 2) void qkv_gemm_kernel(
    const ushort* __restrict__ xs, const ushort* __restrict__ wsb,
    const float* __restrict__ bq, const float* __restrict__ bk,
    const float* __restrict__ bv, ushort* __restrict__ qkv) {
  __shared__ ushort lA[2][16384];  // [buf][256 rows][64]
  __shared__ ushort lB[2][12288];  // [buf][192 rows][64]
  const int t = threadIdx.x;
  const int lane = t & 63, w = t >> 6;
  const int wm = w >> 1, wn = w & 1;          // 4M x 2N wave grid
  const int l15 = lane & 15, l4 = lane >> 4;
  // XCD-chunked swizzle: 256 wgs, 8 XCDs x 32; chunk = 4bm x 8bn
  const int phys = blockIdx.x;
  const int swz = (phys & 7) * 32 + (phys >> 3);
  const int xcd = swz >> 5, jj = swz & 31;
  const int bm = (xcd >> 1) * 4 + (jj >> 3);  // 0..15
  const int bn = (xcd & 1) * 8 + (jj & 7);    // 0..15

  const ushort* Apan = xs + (size_t)(2 * bm) * 16 * 8192;  // two 128-row panels
  const ushort* Bpan = wsb + (size_t)bn * 16 * 12288;

  f32x4 acc[4][6];
#pragma unroll
  for (int i = 0; i < 4; i++)
#pragma unroll
    for (int j = 0; j < 6; j++) acc[i][j] = (f32x4)0.f;

#define STAGE_A(buf, kt)                                                        \
  do {                                                                          \
    const ushort* s0 = Apan + (size_t)(kt) * 8192;                              \
    const ushort* s1 = Apan + (size_t)(16 + (kt)) * 8192;                       \
    async_copy16(&lA[buf][t * 8], s0 + t * 8);                                  \
    async_copy16(&lA[buf][(t + 512) * 8], s0 + (t + 512) * 8);                  \
    async_copy16(&lA[buf][8192 + t * 8], s1 + t * 8);                           \
    async_copy16(&lA[buf][8192 + (t + 512) * 8], s1 + (t + 512) * 8);           \
  } while (0)
#define STAGE_B(buf, kt)                                                        \
  do {                                                                          \
    const ushort* s2 = Bpan + (size_t)(kt) * 12288;                             \
    async_copy16(&lB[buf][t * 8], s2 + t * 8);                                  \
    async_copy16(&lB[buf][(t + 512) * 8], s2 + (t + 512) * 8);                  \
    async_copy16(&lB[buf][(t + 1024) * 8], s2 + (t + 1024) * 8);                \
  } while (0)

  STAGE_A(0, 0);
  STAGE_B(0, 0);
  asm volatile("s_waitcnt vmcnt(0)");
  __builtin_amdgcn_s_barrier();

  for (int kt = 0; kt < 16; ++kt) {
    const int cur = kt & 1;
    // ---- phase 0 (kk = 0) ----
    s16x8 af[4], bfr[6];
#pragma unroll
    for (int mi = 0; mi < 4; mi++) {
      int ra = wm * 64 + mi * 16 + l15;
      int g = l4 ^ (ra & 7);
      af[mi] = *(const s16x8*)&lA[cur][ra * 64 + g * 8];
    }
#pragma unroll
    for (int ni = 0; ni < 6; ni++) {
      int rb = wn * 96 + ni * 16 + l15;
      int g = l4 ^ (rb & 7);
      bfr[ni] = *(const s16x8*)&lB[cur][rb * 64 + g * 8];
    }
    if (kt + 1 < 16) STAGE_A(cur ^ 1, kt + 1);
    __builtin_amdgcn_s_barrier();
    asm volatile("s_waitcnt lgkmcnt(0)");
    __builtin_amdgcn_sched_barrier(0);
    __builtin_amdgcn_s_setprio(1);
#pragma unroll
    for (int mi = 0; mi < 4; mi++)
#pragma unroll
      for (int ni = 0; ni < 6; ni++)
        acc[mi][ni] = __builtin_amdgcn_mfma_f32_16x16x32_bf16(af[mi], bfr[ni], acc[mi][ni], 0, 0, 0);
    __builtin_amdgcn_s_setprio(0);
    __builtin_amdgcn_s_barrier();
    // ---- phase 1 (kk = 1) ----
#pragma unroll
    for (int mi = 0; mi < 4; mi++) {
      int ra = wm * 64 + mi * 16 + l15;
      int g = (4 + l4) ^ (ra & 7);
      af[mi] = *(const s16x8*)&lA[cur][ra * 64 + g * 8];
    }
#pragma unroll
    for (int ni = 0; ni < 6; ni++) {
      int rb = wn * 96 + ni * 16 + l15;
      int g = (4 + l4) ^ (rb & 7);
      bfr[ni] = *(const s16x8*)&lB[cur][rb * 64 + g * 8];
    }
    if (kt + 1 < 16) STAGE_B(cur ^ 1, kt + 1);
    __builtin_amdgcn_s_barrier();
    asm volatile("s_waitcnt lgkmcnt(0)");
    __builtin_amdgcn_sched_barrier(0);
    __builtin_amdgcn_s_setprio(1);
#pragma unroll
    for (int mi = 0; mi < 4; mi++)
#pragma unroll
      for (int ni = 0; ni < 6; ni++)
        acc[mi][ni] = __builtin_amdgcn_mfma_f32_16x16x32_bf16(af[mi], bfr[ni], acc[mi][ni], 0, 0, 0);
    __builtin_amdgcn_s_setprio(0);
    asm volatile("s_waitcnt vmcnt(0)");
    __builtin_amdgcn_s_barrier();
  }
#undef STAGE_A
#undef STAGE_B

  // epilogue: bias, Q-scale, bf16 store to [p][h][s][64]
#pragma unroll
  for (int ni = 0; ni < 6; ni++) {
    int col = bn * 192 + wn * 96 + ni * 16 + l15;  // 0..3071
    int p = col >> 10;
    const float* bias = (p == 0) ? bq : (p == 1) ? bk : bv;
    float b = bias[col & 1023];
    float qscale = (p == 0) ? 0.125f : 1.0f;
    int h = (col >> 6) & 15, dd = col & 63;
    size_t base = ((size_t)(p * 16 + h) * 4096) * 64 + dd;
#pragma unroll
    for (int mi = 0; mi < 4; mi++) {
#pragma unroll
      for (int r = 0; r < 4; r++) {
        int s = bm * 256 + wm * 64 + mi * 16 + l4 * 4 + r;
        float v = (acc[mi][ni][r] + b) * qscale;
        qkv[base + (size_t)s * 64] = f2bf(v);
      }
    }
  }
}

// ---------------- banded flash attention (swapped QK^T, KT=64, dbuf) ----------
__global__ __launch_bounds__(256) void attn_local_kernel(
    const ushort* __restrict__ qkv, float* __restrict__ out) {
  __shared__ ushort lds[2][2][4096];  // [buf][0=K swz,1=V natural][64x64]
  const int bid = blockIdx.x;
  const int wid = (bid & 7) * 128 + (bid >> 3);  // 2 heads per XCD
  const int h = wid >> 6;
  const int q0 = (wid & 63) * 64;
  const int t = threadIdx.x;
  const int lane = t & 63, w = t >> 6;
  const int l15 = lane & 15, l4 = lane >> 4;
  const int qw = q0 + w * 16;
  const int myq = qw + l15;

  const ushort* __restrict__ Q = qkv;
  const ushort* __restrict__ K = qkv + (size_t)16 * 4096 * 64;
  const ushort* __restrict__ V = K + (size_t)16 * 4096 * 64;

  s16x8 qf[2];
  {
    const ushort* qp = &Q[((size_t)h * 4096 + myq) * 64];
    qf[0] = *(const s16x8*)&qp[l4 * 8];
    qf[1] = *(const s16x8*)&qp[32 + l4 * 8];
  }

  f32x4 oacc[4];
#pragma unroll
  for (int i = 0; i < 4; i++) oacc[i] = (f32x4)0.f;
  float mrow = -1e30f, lrow = 0.f;

  const unsigned vtr0 = lds_addr(&lds[0][1][0]) +
      (unsigned)(l4 * 1024 + (l15 >> 2) * 128 + (l15 & 3) * 8);

  int kstart = q0 - 256; if (kstart < 0) kstart = 0;
  int kend = q0 + 320; if (kend > 4096) kend = 4096;

#define STAGE_KV(buf, kb)                                                      \
  do {                                                                         \
    const ushort* Kg = &K[((size_t)h * 4096 + (kb)) * 64];                     \
    const ushort* Vg = &V[((size_t)h * 4096 + (kb)) * 64];                     \
    _Pragma("unroll") for (int i = 0; i < 2; i++) {                            \
      int off = i * 2048 + t * 8;                                              \
      int row = off >> 6;                                                      \
      int c8 = (off >> 3) & 7;                                                 \
      async_copy16(&lds[buf][0][off], &Kg[row * 64 + ((c8 ^ (row & 7)) * 8)]); \
      async_copy16(&lds[buf][1][off], &Vg[off]);                               \
    }                                                                          \
  } while (0)

  STAGE_KV(0, kstart);
  asm volatile("s_waitcnt vmcnt(0)");
  __builtin_amdgcn_s_barrier();

  for (int kb = kstart; kb < kend; kb += 64) {
    const int cur = ((kb - kstart) >> 6) & 1;
    if (kb + 64 < kend) {
      if (cur) STAGE_KV(0, kb + 64); else STAGE_KV(1, kb + 64);
    }
    bool active = (kb + 63 >= qw - 256) && (kb <= qw + 15 + 256);
    if (active) {
      const ushort* lK = &lds[cur][0][0];
      f32x4 st[4];
#pragma unroll
      for (int tt = 0; tt < 4; tt++) st[tt] = (f32x4)0.f;
      __builtin_amdgcn_s_setprio(1);
#pragma unroll
      for (int tt = 0; tt < 4; tt++) {
#pragma unroll
        for (int kc = 0; kc < 2; kc++) {
          int rowk = tt * 16 + l15;
          int g = (kc * 4 + l4) ^ (rowk & 7);
          s16x8 kf = *(const s16x8*)&lK[rowk * 64 + g * 8];
          st[tt] = __builtin_amdgcn_mfma_f32_16x16x32_bf16(kf, qf[kc], st[tt], 0, 0, 0);
        }
      }
      __builtin_amdgcn_s_setprio(0);
      float pe[4][4];
      float rm = -3e38f;
#pragma unroll
      for (int tt = 0; tt < 4; tt++)
#pragma unroll
        for (int r = 0; r < 4; r++) {
          int key = kb + tt * 16 + l4 * 4 + r;
          float s = ((unsigned)(myq - key + 256) <= 512u) ? st[tt][r] : -3e38f;
          pe[tt][r] = s;
          rm = fmaxf(rm, s);
        }
      rm = fmaxf(rm, __shfl_xor(rm, 16));
      rm = fmaxf(rm, __shfl_xor(rm, 32));
      float mn = fmaxf(mrow, rm);
      float sc = __expf(mrow - mn);
      float rs = 0.f;
#pragma unroll
      for (int tt = 0; tt < 4; tt++)
#pragma unroll
        for (int r = 0; r < 4; r++) {
          float e = __expf(pe[tt][r] - mn);
          pe[tt][r] = e;
          rs += e;
        }
      rs += __shfl_xor(rs, 16);
      rs += __shfl_xor(rs, 32);
      mrow = mn;
      lrow = lrow * sc + rs;
      unsigned pk[4][2];
#pragma unroll
      for (int tt = 0; tt < 4; tt++) {
        asm("v_cvt_pk_bf16_f32 %0, %1, %2" : "=v"(pk[tt][0]) : "v"(pe[tt][0]), "v"(pe[tt][1]));
        asm("v_cvt_pk_bf16_f32 %0, %1, %2" : "=v"(pk[tt][1]) : "v"(pe[tt][2]), "v"(pe[tt][3]));
      }
      float scr[4];
#pragma unroll
      for (int r = 0; r < 4; r++) scr[r] = __shfl(sc, l4 * 4 + r);
#pragma unroll
      for (int db = 0; db < 4; db++)
#pragma unroll
        for (int r = 0; r < 4; r++) oacc[db][r] *= scr[r];

      const unsigned vtr = vtr0 + (unsigned)cur * 16384u;
#pragma unroll
      for (int c = 0; c < 2; c++) {
        u32x2 t00, t01, t10, t11, t20, t21, t30, t31;
        if (c == 0) {
          TRRD(t00, vtr, 0);    TRRD(t01, vtr, 512);
          TRRD(t10, vtr, 32);   TRRD(t11, vtr, 544);
          TRRD(t20, vtr, 64);   TRRD(t21, vtr, 576);
          TRRD(t30, vtr, 96);   TRRD(t31, vtr, 608);
        } else {
          TRRD(t00, vtr, 4096); TRRD(t01, vtr, 4608);
          TRRD(t10, vtr, 4128); TRRD(t11, vtr, 4640);
          TRRD(t20, vtr, 4160); TRRD(t21, vtr, 4672);
          TRRD(t30, vtr, 4192); TRRD(t31, vtr, 4704);
        }
        const int srcA = ((lane & 16) << 1) | l15;
        const int srcB = srcA + 16;
        const int tsel = (lane >> 5) & 1;
        unsigned x0 = (unsigned)__shfl((int)pk[2 * c][0], srcA);
        unsigned y0 = (unsigned)__shfl((int)pk[2 * c + 1][0], srcA);
        unsigned x1 = (unsigned)__shfl((int)pk[2 * c][1], srcA);
        unsigned y1 = (unsigned)__shfl((int)pk[2 * c + 1][1], srcA);
        unsigned x2 = (unsigned)__shfl((int)pk[2 * c][0], srcB);
        unsigned y2 = (unsigned)__shfl((int)pk[2 * c + 1][0], srcB);
        unsigned x3 = (unsigned)__shfl((int)pk[2 * c][1], srcB);
        unsigned y3 = (unsigned)__shfl((int)pk[2 * c + 1][1], srcB);
        U8 pf;
        pf.u[0] = tsel ? y0 : x0;
        pf.u[1] = tsel ? y1 : x1;
        pf.u[2] = tsel ? y2 : x2;
        pf.u[3] = tsel ? y3 : x3;
        asm volatile("s_waitcnt lgkmcnt(0)");
        __builtin_amdgcn_sched_barrier(0);
        U8 vf0, vf1, vf2, vf3;
        vf0.u[0] = t00[0]; vf0.u[1] = t00[1]; vf0.u[2] = t01[0]; vf0.u[3] = t01[1];
        vf1.u[0] = t10[0]; vf1.u[1] = t10[1]; vf1.u[2] = t11[0]; vf1.u[3] = t11[1];
        vf2.u[0] = t20[0]; vf2.u[1] = t20[1]; vf2.u[2] = t21[0]; vf2.u[3] = t21[1];
        vf3.u[0] = t30[0]; vf3.u[1] = t30[1]; vf3.u[2] = t31[0]; vf3.u[3] = t31[1];
        __builtin_amdgcn_s_setprio(1);
        oacc[0] = __builtin_amdgcn_mfma_f32_16x16x32_bf16(pf.v, vf0.v, oacc[0], 0, 0, 0);
        oacc[1] = __builtin_amdgcn_mfma_f32_16x16x32_bf16(pf.v, vf1.v, oacc[1], 0, 0, 0);
        oacc[2] = __builtin_amdgcn_mfma_f32_16x16x32_bf16(pf.v, vf2.v, oacc[2], 0, 0, 0);
        oacc[3] = __builtin_amdgcn_mfma_f32_16x16x32_bf16(pf.v, vf3.v, oacc[3], 0, 0, 0);
        __builtin_amdgcn_s_setprio(0);
      }
    }
    asm volatile("s_waitcnt vmcnt(0)");
    __builtin_amdgcn_s_barrier();
  }
#undef STAGE_KV
  float linv[4];
#pragma unroll
  for (int r = 0; r < 4; r++) linv[r] = 1.0f / __shfl(lrow, l4 * 4 + r);
#pragma unroll
  for (int db = 0; db < 4; db++)
#pragma unroll
    for (int r = 0; r < 4; r++) {
      int s = qw + l4 * 4 + r;
      out[(size_t)s * 1024 + h * 64 + db * 16 + l15] = oacc[db][r] * linv[r];
    }
}

extern "C" void kernel_launch(void* const* d_in, const int* in_sizes, int n_in,
                              void* d_out, int out_size, void* d_ws, size_t ws_size,
                              hipStream_t stream) {
  const float* x  = (const float*)d_in[0];
  const float* Wq = (const float*)d_in[1];
  const float* bq = (const float*)d_in[2];
  const float* Wk = (const float*)d_in[3];
  const float* bk = (const float*)d_in[4];
  const float* Wv = (const float*)d_in[5];
  const float* bv = (const float*)d_in[6];

  ushort* qkv = (ushort*)d_ws;                                   // 24 MB
  ushort* xs  = (ushort*)((char*)d_ws + (size_t)25165824);       // 8 MB
  ushort* wsb = xs + (size_t)4096 * 1024;                        // 6 MB
  float* out = (float*)d_out;

  convert_x_kernel<<<2048, 256, 0, stream>>>(x, xs);
  convert_w_kernel<<<1536, 256, 0, stream>>>(Wq, Wk, Wv, wsb);
  qkv_gemm_kernel<<<256, 512, 0, stream>>>(xs, wsb, bq, bk, bv, qkv);
  attn_local_kernel<<<1024, 256, 0, stream>>>(qkv, out);
}

// Round 6
// 69.298 us; speedup vs baseline: 1.6885x; 1.0803x over previous
//
#include <hip/hip_runtime.h>
#include <hip/hip_bf16.h>

typedef __attribute__((ext_vector_type(4))) float f32x4;
typedef __attribute__((ext_vector_type(8))) short s16x8;
typedef __attribute__((ext_vector_type(4))) float float4_t;
typedef __attribute__((ext_vector_type(2))) unsigned int u32x2;

union U8 { s16x8 v; unsigned u[4]; };

__device__ __forceinline__ ushort f2bf(float f) {
  union { float f; unsigned u; } v; v.f = f;
  unsigned r = v.u + 0x7fffu + ((v.u >> 16) & 1u);
  return (ushort)(r >> 16);
}

__device__ __forceinline__ void async_copy16(ushort* lds, const ushort* g) {
  __builtin_amdgcn_global_load_lds(
      (const __attribute__((address_space(1))) unsigned int*)g,
      (__attribute__((address_space(3))) unsigned int*)lds, 16, 0, 0);
}

__device__ __forceinline__ unsigned lds_addr(const void* p) {
  return (unsigned)(unsigned long long)(__attribute__((address_space(3))) const void*)p;
}

#define TRRD(dst, addr, off_lit) \
  asm volatile("ds_read_b64_tr_b16 %0, %1 offset:" #off_lit : "=v"(dst) : "v"(addr))

// ---------- merged f32 -> bf16 pre-swizzled panel conversion ----------
// x panels: [tm 32][tk 16][128][64]; W panels: [tn3 16][tk 16][192][64].
// Row r chunk c8 stored at (c8 ^ (r&7)).
__global__ __launch_bounds__(256) void convert_kernel(
    const float* __restrict__ x, const float* __restrict__ Wq,
    const float* __restrict__ Wk, const float* __restrict__ Wv,
    ushort* __restrict__ xs, ushort* __restrict__ ws) {
  int b = blockIdx.x;
  if (b < 2048) {
    int c = b * 256 + threadIdx.x;
    int kc = c & 127;
    int m = c >> 7;
    const float4_t* s = (const float4_t*)&x[(size_t)m * 1024 + kc * 8];
    float4_t a0 = s[0], a1 = s[1];
    s16x8 v;
    v[0] = (short)f2bf(a0[0]); v[1] = (short)f2bf(a0[1]);
    v[2] = (short)f2bf(a0[2]); v[3] = (short)f2bf(a0[3]);
    v[4] = (short)f2bf(a1[0]); v[5] = (short)f2bf(a1[1]);
    v[6] = (short)f2bf(a1[2]); v[7] = (short)f2bf(a1[3]);
    int tm = m >> 7, tk = kc >> 3, r = m & 127, c8 = kc & 7;
    *(s16x8*)&xs[((size_t)(tm * 16 + tk) * 128 + r) * 64 + ((c8 ^ (r & 7)) * 8)] = v;
  } else {
    int c = (b - 2048) * 256 + threadIdx.x;
    int kc = c & 127;
    int n = c >> 7;
    int p = n >> 10, nW = n & 1023;
    const float* __restrict__ W = (p == 0) ? Wq : (p == 1) ? Wk : Wv;
    const float4_t* s = (const float4_t*)&W[(size_t)nW * 1024 + kc * 8];
    float4_t a0 = s[0], a1 = s[1];
    s16x8 v;
    v[0] = (short)f2bf(a0[0]); v[1] = (short)f2bf(a0[1]);
    v[2] = (short)f2bf(a0[2]); v[3] = (short)f2bf(a0[3]);
    v[4] = (short)f2bf(a1[0]); v[5] = (short)f2bf(a1[1]);
    v[6] = (short)f2bf(a1[2]); v[7] = (short)f2bf(a1[3]);
    unsigned tn3 = (unsigned)n / 192u;
    unsigned r = (unsigned)n - tn3 * 192u;
    int tk = kc >> 3, c8 = kc & 7;
    *(s16x8*)&ws[((size_t)(tn3 * 16 + tk) * 192 + r) * 64 + ((c8 ^ (r & 7)) * 8)] = v;
  }
}

// ---------------- fused QKV GEMM: 256x192 tile, BK=64, 8 waves, dbuf pipeline ----
__global__ __launch_bounds__(512, 2) void qkv_gemm_kernel(
    const ushort* __restrict__ xs, const ushort* __restrict__ wsb,
    const float* __restrict__ bq, const float* __restrict__ bk,
    const float* __restrict__ bv, ushort* __restrict__ qkv) {
  __shared__ ushort lA[2][16384];  // [buf][256 rows][64]
  __shared__ ushort lB[2][12288];  // [buf][192 rows][64]
  const int t = threadIdx.x;
  const int lane = t & 63, w = t >> 6;
  const int wm = w >> 1, wn = w & 1;          // 4M x 2N wave grid
  const int l15 = lane & 15, l4 = lane >> 4;
  const int phys = blockIdx.x;
  const int swz = (phys & 7) * 32 + (phys >> 3);
  const int xcd = swz >> 5, jj = swz & 31;
  const int bm = (xcd >> 1) * 4 + (jj >> 3);
  const int bn = (xcd & 1) * 8 + (jj & 7);

  const ushort* Apan = xs + (size_t)(2 * bm) * 16 * 8192;
  const ushort* Bpan = wsb + (size_t)bn * 16 * 12288;

  f32x4 acc[4][6];
#pragma unroll
  for (int i = 0; i < 4; i++)
#pragma unroll
    for (int j = 0; j < 6; j++) acc[i][j] = (f32x4)0.f;

#define STAGE_A(buf, kt)                                                        \
  do {                                                                          \
    const ushort* s0 = Apan + (size_t)(kt) * 8192;                              \
    const ushort* s1 = Apan + (size_t)(16 + (kt)) * 8192;                       \
    async_copy16(&lA[buf][t * 8], s0 + t * 8);                                  \
    async_copy16(&lA[buf][(t + 512) * 8], s0 + (t + 512) * 8);                  \
    async_copy16(&lA[buf][8192 + t * 8], s1 + t * 8);                           \
    async_copy16(&lA[buf][8192 + (t + 512) * 8], s1 + (t + 512) * 8);           \
  } while (0)
#define STAGE_B(buf, kt)                                                        \
  do {                                                                          \
    const ushort* s2 = Bpan + (size_t)(kt) * 12288;                             \
    async_copy16(&lB[buf][t * 8], s2 + t * 8);                                  \
    async_copy16(&lB[buf][(t + 512) * 8], s2 + (t + 512) * 8);                  \
    async_copy16(&lB[buf][(t + 1024) * 8], s2 + (t + 1024) * 8);                \
  } while (0)

  STAGE_A(0, 0);
  STAGE_B(0, 0);
  asm volatile("s_waitcnt vmcnt(0)");
  __builtin_amdgcn_s_barrier();

  for (int kt = 0; kt < 16; ++kt) {
    const int cur = kt & 1;
    s16x8 af[4], bfr[6];
#pragma unroll
    for (int mi = 0; mi < 4; mi++) {
      int ra = wm * 64 + mi * 16 + l15;
      int g = l4 ^ (ra & 7);
      af[mi] = *(const s16x8*)&lA[cur][ra * 64 + g * 8];
    }
#pragma unroll
    for (int ni = 0; ni < 6; ni++) {
      int rb = wn * 96 + ni * 16 + l15;
      int g = l4 ^ (rb & 7);
      bfr[ni] = *(const s16x8*)&lB[cur][rb * 64 + g * 8];
    }
    if (kt + 1 < 16) STAGE_A(cur ^ 1, kt + 1);
    __builtin_amdgcn_s_barrier();
    asm volatile("s_waitcnt lgkmcnt(0)");
    __builtin_amdgcn_sched_barrier(0);
    __builtin_amdgcn_s_setprio(1);
#pragma unroll
    for (int mi = 0; mi < 4; mi++)
#pragma unroll
      for (int ni = 0; ni < 6; ni++)
        acc[mi][ni] = __builtin_amdgcn_mfma_f32_16x16x32_bf16(af[mi], bfr[ni], acc[mi][ni], 0, 0, 0);
    __builtin_amdgcn_s_setprio(0);
    __builtin_amdgcn_s_barrier();
#pragma unroll
    for (int mi = 0; mi < 4; mi++) {
      int ra = wm * 64 + mi * 16 + l15;
      int g = (4 + l4) ^ (ra & 7);
      af[mi] = *(const s16x8*)&lA[cur][ra * 64 + g * 8];
    }
#pragma unroll
    for (int ni = 0; ni < 6; ni++) {
      int rb = wn * 96 + ni * 16 + l15;
      int g = (4 + l4) ^ (rb & 7);
      bfr[ni] = *(const s16x8*)&lB[cur][rb * 64 + g * 8];
    }
    if (kt + 1 < 16) STAGE_B(cur ^ 1, kt + 1);
    __builtin_amdgcn_s_barrier();
    asm volatile("s_waitcnt lgkmcnt(0)");
    __builtin_amdgcn_sched_barrier(0);
    __builtin_amdgcn_s_setprio(1);
#pragma unroll
    for (int mi = 0; mi < 4; mi++)
#pragma unroll
      for (int ni = 0; ni < 6; ni++)
        acc[mi][ni] = __builtin_amdgcn_mfma_f32_16x16x32_bf16(af[mi], bfr[ni], acc[mi][ni], 0, 0, 0);
    __builtin_amdgcn_s_setprio(0);
    asm volatile("s_waitcnt vmcnt(0)");
    __builtin_amdgcn_s_barrier();
  }
#undef STAGE_A
#undef STAGE_B

  // epilogue: bias, Q-scale (0.125 * log2e -> exp2-domain scores), bf16 store
#pragma unroll
  for (int ni = 0; ni < 6; ni++) {
    int col = bn * 192 + wn * 96 + ni * 16 + l15;
    int p = col >> 10;
    const float* bias = (p == 0) ? bq : (p == 1) ? bk : bv;
    float b = bias[col & 1023];
    float qscale = (p == 0) ? 0.125f * 1.44269504f : 1.0f;
    int h = (col >> 6) & 15, dd = col & 63;
    size_t base = ((size_t)(p * 16 + h) * 4096) * 64 + dd;
#pragma unroll
    for (int mi = 0; mi < 4; mi++) {
#pragma unroll
      for (int r = 0; r < 4; r++) {
        int s = bm * 256 + wm * 64 + mi * 16 + l4 * 4 + r;
        float v = (acc[mi][ni][r] + b) * qscale;
        qkv[base + (size_t)s * 64] = f2bf(v);
      }
    }
  }
}

// ---------------- banded flash attention (swapped QK^T, KT=64, dbuf) ----------
// exp2-domain scores; ones-column MFMA computes softmax denominator.
__global__ __launch_bounds__(256) void attn_local_kernel(
    const ushort* __restrict__ qkv, float* __restrict__ out) {
  __shared__ ushort lds[2][2][4096];  // [buf][0=K swz,1=V natural][64x64]
  const int bid = blockIdx.x;
  const int wid = (bid & 7) * 128 + (bid >> 3);  // 2 heads per XCD
  const int h = wid >> 6;
  const int q0 = (wid & 63) * 64;
  const int t = threadIdx.x;
  const int lane = t & 63, w = t >> 6;
  const int l15 = lane & 15, l4 = lane >> 4;
  const int qw = q0 + w * 16;
  const int myq = qw + l15;

  const ushort* __restrict__ Q = qkv;
  const ushort* __restrict__ K = qkv + (size_t)16 * 4096 * 64;
  const ushort* __restrict__ V = K + (size_t)16 * 4096 * 64;

  s16x8 qf[2];
  {
    const ushort* qp = &Q[((size_t)h * 4096 + myq) * 64];
    qf[0] = *(const s16x8*)&qp[l4 * 8];
    qf[1] = *(const s16x8*)&qp[32 + l4 * 8];
  }

  // ones B-operand: B[k][col] = (col==0) ? 1.0bf : 0  -> denominator column
  U8 ones;
  {
    unsigned w1 = (l15 == 0) ? 0x3F803F80u : 0u;
    ones.u[0] = w1; ones.u[1] = w1; ones.u[2] = w1; ones.u[3] = w1;
  }

  f32x4 oacc[5];  // [0..3]: d-blocks; [4]: row-sum column (valid at l15==0)
#pragma unroll
  for (int i = 0; i < 5; i++) oacc[i] = (f32x4)0.f;
  float mrow = -1e30f;

  const unsigned vtr0 = lds_addr(&lds[0][1][0]) +
      (unsigned)(l4 * 1024 + (l15 >> 2) * 128 + (l15 & 3) * 8);

  int kstart = q0 - 256; if (kstart < 0) kstart = 0;
  int kend = q0 + 320; if (kend > 4096) kend = 4096;

#define STAGE_KV(buf, kb)                                                      \
  do {                                                                         \
    const ushort* Kg = &K[((size_t)h * 4096 + (kb)) * 64];                     \
    const ushort* Vg = &V[((size_t)h * 4096 + (kb)) * 64];                     \
    _Pragma("unroll") for (int i = 0; i < 2; i++) {                            \
      int off = i * 2048 + t * 8;                                              \
      int row = off >> 6;                                                      \
      int c8 = (off >> 3) & 7;                                                 \
      async_copy16(&lds[buf][0][off], &Kg[row * 64 + ((c8 ^ (row & 7)) * 8)]); \
      async_copy16(&lds[buf][1][off], &Vg[off]);                               \
    }                                                                          \
  } while (0)

  STAGE_KV(0, kstart);
  asm volatile("s_waitcnt vmcnt(0)");
  __builtin_amdgcn_s_barrier();

  for (int kb = kstart; kb < kend; kb += 64) {
    const int cur = ((kb - kstart) >> 6) & 1;
    if (kb + 64 < kend) {
      if (cur) STAGE_KV(0, kb + 64); else STAGE_KV(1, kb + 64);
    }
    bool active = (kb + 63 >= qw - 256) && (kb <= qw + 15 + 256);
    if (active) {
      const ushort* lK = &lds[cur][0][0];
      f32x4 st[4];
#pragma unroll
      for (int tt = 0; tt < 4; tt++) st[tt] = (f32x4)0.f;
      __builtin_amdgcn_s_setprio(1);
#pragma unroll
      for (int tt = 0; tt < 4; tt++) {
#pragma unroll
        for (int kc = 0; kc < 2; kc++) {
          int rowk = tt * 16 + l15;
          int g = (kc * 4 + l4) ^ (rowk & 7);
          s16x8 kf = *(const s16x8*)&lK[rowk * 64 + g * 8];
          st[tt] = __builtin_amdgcn_mfma_f32_16x16x32_bf16(kf, qf[kc], st[tt], 0, 0, 0);
        }
      }
      __builtin_amdgcn_s_setprio(0);
      float pe[4][4];
      // interior tiles (wave-uniform): no masking needed
      const bool interior = (kb >= qw - 241) && (kb <= qw + 193);
      if (interior) {
#pragma unroll
        for (int tt = 0; tt < 4; tt++)
#pragma unroll
          for (int r = 0; r < 4; r++) pe[tt][r] = st[tt][r];
      } else {
#pragma unroll
        for (int tt = 0; tt < 4; tt++)
#pragma unroll
          for (int r = 0; r < 4; r++) {
            int key = kb + tt * 16 + l4 * 4 + r;
            pe[tt][r] = ((unsigned)(myq - key + 256) <= 512u) ? st[tt][r] : -3e38f;
          }
      }
      // row max (tree) + cross-group reduce
      float m0 = fmaxf(fmaxf(pe[0][0], pe[0][1]), fmaxf(pe[0][2], pe[0][3]));
      float m1 = fmaxf(fmaxf(pe[1][0], pe[1][1]), fmaxf(pe[1][2], pe[1][3]));
      float m2 = fmaxf(fmaxf(pe[2][0], pe[2][1]), fmaxf(pe[2][2], pe[2][3]));
      float m3 = fmaxf(fmaxf(pe[3][0], pe[3][1]), fmaxf(pe[3][2], pe[3][3]));
      float rm = fmaxf(fmaxf(m0, m1), fmaxf(m2, m3));
      rm = fmaxf(rm, __shfl_xor(rm, 16));
      rm = fmaxf(rm, __shfl_xor(rm, 32));
      // defer-max: rescale only if some row grew by > 8 (log2 domain)
      if (__any(rm > mrow + 8.0f)) {
        float mn = fmaxf(mrow, rm);
        float sc = __builtin_amdgcn_exp2f(mrow - mn);
        mrow = mn;
        float scr[4];
#pragma unroll
        for (int r = 0; r < 4; r++) scr[r] = __shfl(sc, l4 * 4 + r);
#pragma unroll
        for (int db = 0; db < 5; db++)
#pragma unroll
          for (int r = 0; r < 4; r++) oacc[db][r] *= scr[r];
      }
      // P = exp2(s - m), pack to bf16 pairs
      unsigned pk[4][2];
#pragma unroll
      for (int tt = 0; tt < 4; tt++) {
        float e0 = __builtin_amdgcn_exp2f(pe[tt][0] - mrow);
        float e1 = __builtin_amdgcn_exp2f(pe[tt][1] - mrow);
        float e2 = __builtin_amdgcn_exp2f(pe[tt][2] - mrow);
        float e3 = __builtin_amdgcn_exp2f(pe[tt][3] - mrow);
        asm("v_cvt_pk_bf16_f32 %0, %1, %2" : "=v"(pk[tt][0]) : "v"(e0), "v"(e1));
        asm("v_cvt_pk_bf16_f32 %0, %1, %2" : "=v"(pk[tt][1]) : "v"(e2), "v"(e3));
      }

      const unsigned vtr = vtr0 + (unsigned)cur * 16384u;
#pragma unroll
      for (int c = 0; c < 2; c++) {
        u32x2 t00, t01, t10, t11, t20, t21, t30, t31;
        if (c == 0) {
          TRRD(t00, vtr, 0);    TRRD(t01, vtr, 512);
          TRRD(t10, vtr, 32);   TRRD(t11, vtr, 544);
          TRRD(t20, vtr, 64);   TRRD(t21, vtr, 576);
          TRRD(t30, vtr, 96);   TRRD(t31, vtr, 608);
        } else {
          TRRD(t00, vtr, 4096); TRRD(t01, vtr, 4608);
          TRRD(t10, vtr, 4128); TRRD(t11, vtr, 4640);
          TRRD(t20, vtr, 4160); TRRD(t21, vtr, 4672);
          TRRD(t30, vtr, 4192); TRRD(t31, vtr, 4704);
        }
        const int srcA = ((lane & 16) << 1) | l15;
        const int srcB = srcA + 16;
        const int tsel = (lane >> 5) & 1;
        unsigned x0 = (unsigned)__shfl((int)pk[2 * c][0], srcA);
        unsigned y0 = (unsigned)__shfl((int)pk[2 * c + 1][0], srcA);
        unsigned x1 = (unsigned)__shfl((int)pk[2 * c][1], srcA);
        unsigned y1 = (unsigned)__shfl((int)pk[2 * c + 1][1], srcA);
        unsigned x2 = (unsigned)__shfl((int)pk[2 * c][0], srcB);
        unsigned y2 = (unsigned)__shfl((int)pk[2 * c + 1][0], srcB);
        unsigned x3 = (unsigned)__shfl((int)pk[2 * c][1], srcB);
        unsigned y3 = (unsigned)__shfl((int)pk[2 * c + 1][1], srcB);
        U8 pf;
        pf.u[0] = tsel ? y0 : x0;
        pf.u[1] = tsel ? y1 : x1;
        pf.u[2] = tsel ? y2 : x2;
        pf.u[3] = tsel ? y3 : x3;
        asm volatile("s_waitcnt lgkmcnt(0)");
        __builtin_amdgcn_sched_barrier(0);
        U8 vf0, vf1, vf2, vf3;
        vf0.u[0] = t00[0]; vf0.u[1] = t00[1]; vf0.u[2] = t01[0]; vf0.u[3] = t01[1];
        vf1.u[0] = t10[0]; vf1.u[1] = t10[1]; vf1.u[2] = t11[0]; vf1.u[3] = t11[1];
        vf2.u[0] = t20[0]; vf2.u[1] = t20[1]; vf2.u[2] = t21[0]; vf2.u[3] = t21[1];
        vf3.u[0] = t30[0]; vf3.u[1] = t30[1]; vf3.u[2] = t31[0]; vf3.u[3] = t31[1];
        __builtin_amdgcn_s_setprio(1);
        oacc[0] = __builtin_amdgcn_mfma_f32_16x16x32_bf16(pf.v, vf0.v, oacc[0], 0, 0, 0);
        oacc[1] = __builtin_amdgcn_mfma_f32_16x16x32_bf16(pf.v, vf1.v, oacc[1], 0, 0, 0);
        oacc[2] = __builtin_amdgcn_mfma_f32_16x16x32_bf16(pf.v, vf2.v, oacc[2], 0, 0, 0);
        oacc[3] = __builtin_amdgcn_mfma_f32_16x16x32_bf16(pf.v, vf3.v, oacc[3], 0, 0, 0);
        oacc[4] = __builtin_amdgcn_mfma_f32_16x16x32_bf16(pf.v, ones.v, oacc[4], 0, 0, 0);
        __builtin_amdgcn_s_setprio(0);
      }
    }
    asm volatile("s_waitcnt vmcnt(0)");
    __builtin_amdgcn_s_barrier();
  }
#undef STAGE_KV
  // epilogue: normalize by denominator column (lives at l15==0 of own l4 group)
  float linv[4];
#pragma unroll
  for (int r = 0; r < 4; r++) linv[r] = 1.0f / __shfl(oacc[4][r], lane & 48);
#pragma unroll
  for (int db = 0; db < 4; db++)
#pragma unroll
    for (int r = 0; r < 4; r++) {
      int s = qw + l4 * 4 + r;
      out[(size_t)s * 1024 + h * 64 + db * 16 + l15] = oacc[db][r] * linv[r];
    }
}

extern "C" void kernel_launch(void* const* d_in, const int* in_sizes, int n_in,
                              void* d_out, int out_size, void* d_ws, size_t ws_size,
                              hipStream_t stream) {
  const float* x  = (const float*)d_in[0];
  const float* Wq = (const float*)d_in[1];
  const float* bq = (const float*)d_in[2];
  const float* Wk = (const float*)d_in[3];
  const float* bk = (const float*)d_in[4];
  const float* Wv = (const float*)d_in[5];
  const float* bv = (const float*)d_in[6];

  ushort* qkv = (ushort*)d_ws;                                   // 24 MB
  ushort* xs  = (ushort*)((char*)d_ws + (size_t)25165824);       // 8 MB
  ushort* wsb = xs + (size_t)4096 * 1024;                        // 6 MB
  float* out = (float*)d_out;

  convert_kernel<<<3584, 256, 0, stream>>>(x, Wq, Wk, Wv, xs, wsb);
  qkv_gemm_kernel<<<256, 512, 0, stream>>>(xs, wsb, bq, bk, bv, qkv);
  attn_local_kernel<<<1024, 256, 0, stream>>>(qkv, out);
}

// Round 7
// 69.206 us; speedup vs baseline: 1.6907x; 1.0013x over previous
//
#include <hip/hip_runtime.h>
#include <hip/hip_bf16.h>

typedef __attribute__((ext_vector_type(4))) float f32x4;
typedef __attribute__((ext_vector_type(8))) short s16x8;
typedef __attribute__((ext_vector_type(4))) float float4_t;
typedef __attribute__((ext_vector_type(2))) unsigned int u32x2;

union U8 { s16x8 v; unsigned u[4]; };

__device__ __forceinline__ ushort f2bf(float f) {
  union { float f; unsigned u; } v; v.f = f;
  unsigned r = v.u + 0x7fffu + ((v.u >> 16) & 1u);
  return (ushort)(r >> 16);
}

__device__ __forceinline__ void async_copy16(ushort* lds, const ushort* g) {
  __builtin_amdgcn_global_load_lds(
      (const __attribute__((address_space(1))) unsigned int*)g,
      (__attribute__((address_space(3))) unsigned int*)lds, 16, 0, 0);
}

__device__ __forceinline__ unsigned lds_addr(const void* p) {
  return (unsigned)(unsigned long long)(__attribute__((address_space(3))) const void*)p;
}

#define TRRD(dst, addr, off_lit) \
  asm volatile("ds_read_b64_tr_b16 %0, %1 offset:" #off_lit : "=v"(dst) : "v"(addr))

// ---------- merged f32 -> bf16 pre-swizzled panel conversion ----------
__global__ __launch_bounds__(256) void convert_kernel(
    const float* __restrict__ x, const float* __restrict__ Wq,
    const float* __restrict__ Wk, const float* __restrict__ Wv,
    ushort* __restrict__ xs, ushort* __restrict__ ws) {
  int b = blockIdx.x;
  if (b < 2048) {
    int c = b * 256 + threadIdx.x;
    int kc = c & 127;
    int m = c >> 7;
    const float4_t* s = (const float4_t*)&x[(size_t)m * 1024 + kc * 8];
    float4_t a0 = s[0], a1 = s[1];
    s16x8 v;
    v[0] = (short)f2bf(a0[0]); v[1] = (short)f2bf(a0[1]);
    v[2] = (short)f2bf(a0[2]); v[3] = (short)f2bf(a0[3]);
    v[4] = (short)f2bf(a1[0]); v[5] = (short)f2bf(a1[1]);
    v[6] = (short)f2bf(a1[2]); v[7] = (short)f2bf(a1[3]);
    int tm = m >> 7, tk = kc >> 3, r = m & 127, c8 = kc & 7;
    *(s16x8*)&xs[((size_t)(tm * 16 + tk) * 128 + r) * 64 + ((c8 ^ (r & 7)) * 8)] = v;
  } else {
    int c = (b - 2048) * 256 + threadIdx.x;
    int kc = c & 127;
    int n = c >> 7;
    int p = n >> 10, nW = n & 1023;
    const float* __restrict__ W = (p == 0) ? Wq : (p == 1) ? Wk : Wv;
    const float4_t* s = (const float4_t*)&W[(size_t)nW * 1024 + kc * 8];
    float4_t a0 = s[0], a1 = s[1];
    s16x8 v;
    v[0] = (short)f2bf(a0[0]); v[1] = (short)f2bf(a0[1]);
    v[2] = (short)f2bf(a0[2]); v[3] = (short)f2bf(a0[3]);
    v[4] = (short)f2bf(a1[0]); v[5] = (short)f2bf(a1[1]);
    v[6] = (short)f2bf(a1[2]); v[7] = (short)f2bf(a1[3]);
    unsigned tn3 = (unsigned)n / 192u;
    unsigned r = (unsigned)n - tn3 * 192u;
    int tk = kc >> 3, c8 = kc & 7;
    *(s16x8*)&ws[((size_t)(tn3 * 16 + tk) * 192 + r) * 64 + ((c8 ^ (r & 7)) * 8)] = v;
  }
}

// ---------------- fused QKV GEMM: 256x192 tile, BK=64, 8 waves, dbuf pipeline ----
__global__ __launch_bounds__(512, 2) void qkv_gemm_kernel(
    const ushort* __restrict__ xs, const ushort* __restrict__ wsb,
    const float* __restrict__ bq, const float* __restrict__ bk,
    const float* __restrict__ bv, ushort* __restrict__ qkv) {
  __shared__ ushort lA[2][16384];  // [buf][256 rows][64]
  __shared__ ushort lB[2][12288];  // [buf][192 rows][64]
  const int t = threadIdx.x;
  const int lane = t & 63, w = t >> 6;
  const int wm = w >> 1, wn = w & 1;
  const int l15 = lane & 15, l4 = lane >> 4;
  const int phys = blockIdx.x;
  const int swz = (phys & 7) * 32 + (phys >> 3);
  const int xcd = swz >> 5, jj = swz & 31;
  const int bm = (xcd >> 1) * 4 + (jj >> 3);
  const int bn = (xcd & 1) * 8 + (jj & 7);

  const ushort* Apan = xs + (size_t)(2 * bm) * 16 * 8192;
  const ushort* Bpan = wsb + (size_t)bn * 16 * 12288;

  f32x4 acc[4][6];
#pragma unroll
  for (int i = 0; i < 4; i++)
#pragma unroll
    for (int j = 0; j < 6; j++) acc[i][j] = (f32x4)0.f;

#define STAGE_A(buf, kt)                                                        \
  do {                                                                          \
    const ushort* s0 = Apan + (size_t)(kt) * 8192;                              \
    const ushort* s1 = Apan + (size_t)(16 + (kt)) * 8192;                       \
    async_copy16(&lA[buf][t * 8], s0 + t * 8);                                  \
    async_copy16(&lA[buf][(t + 512) * 8], s0 + (t + 512) * 8);                  \
    async_copy16(&lA[buf][8192 + t * 8], s1 + t * 8);                           \
    async_copy16(&lA[buf][8192 + (t + 512) * 8], s1 + (t + 512) * 8);           \
  } while (0)
#define STAGE_B(buf, kt)                                                        \
  do {                                                                          \
    const ushort* s2 = Bpan + (size_t)(kt) * 12288;                             \
    async_copy16(&lB[buf][t * 8], s2 + t * 8);                                  \
    async_copy16(&lB[buf][(t + 512) * 8], s2 + (t + 512) * 8);                  \
    async_copy16(&lB[buf][(t + 1024) * 8], s2 + (t + 1024) * 8);                \
  } while (0)

  STAGE_A(0, 0);
  STAGE_B(0, 0);
  asm volatile("s_waitcnt vmcnt(0)");
  __builtin_amdgcn_s_barrier();

  for (int kt = 0; kt < 16; ++kt) {
    const int cur = kt & 1;
    // ---- phase 0 (kk = 0): issue BOTH next-tile stages, max vmcnt slack ----
    s16x8 af[4], bfr[6];
#pragma unroll
    for (int mi = 0; mi < 4; mi++) {
      int ra = wm * 64 + mi * 16 + l15;
      int g = l4 ^ (ra & 7);
      af[mi] = *(const s16x8*)&lA[cur][ra * 64 + g * 8];
    }
#pragma unroll
    for (int ni = 0; ni < 6; ni++) {
      int rb = wn * 96 + ni * 16 + l15;
      int g = l4 ^ (rb & 7);
      bfr[ni] = *(const s16x8*)&lB[cur][rb * 64 + g * 8];
    }
    if (kt + 1 < 16) {
      STAGE_A(cur ^ 1, kt + 1);
      STAGE_B(cur ^ 1, kt + 1);
    }
    __builtin_amdgcn_s_barrier();
    asm volatile("s_waitcnt lgkmcnt(0)");
    __builtin_amdgcn_sched_barrier(0);
    __builtin_amdgcn_s_setprio(1);
#pragma unroll
    for (int mi = 0; mi < 4; mi++)
#pragma unroll
      for (int ni = 0; ni < 6; ni++)
        acc[mi][ni] = __builtin_amdgcn_mfma_f32_16x16x32_bf16(af[mi], bfr[ni], acc[mi][ni], 0, 0, 0);
    __builtin_amdgcn_s_setprio(0);
    __builtin_amdgcn_s_barrier();
    // ---- phase 1 (kk = 1) ----
#pragma unroll
    for (int mi = 0; mi < 4; mi++) {
      int ra = wm * 64 + mi * 16 + l15;
      int g = (4 + l4) ^ (ra & 7);
      af[mi] = *(const s16x8*)&lA[cur][ra * 64 + g * 8];
    }
#pragma unroll
    for (int ni = 0; ni < 6; ni++) {
      int rb = wn * 96 + ni * 16 + l15;
      int g = (4 + l4) ^ (rb & 7);
      bfr[ni] = *(const s16x8*)&lB[cur][rb * 64 + g * 8];
    }
    __builtin_amdgcn_s_barrier();
    asm volatile("s_waitcnt lgkmcnt(0)");
    __builtin_amdgcn_sched_barrier(0);
    __builtin_amdgcn_s_setprio(1);
#pragma unroll
    for (int mi = 0; mi < 4; mi++)
#pragma unroll
      for (int ni = 0; ni < 6; ni++)
        acc[mi][ni] = __builtin_amdgcn_mfma_f32_16x16x32_bf16(af[mi], bfr[ni], acc[mi][ni], 0, 0, 0);
    __builtin_amdgcn_s_setprio(0);
    asm volatile("s_waitcnt vmcnt(0)");
    __builtin_amdgcn_s_barrier();
  }
#undef STAGE_A
#undef STAGE_B

  // epilogue: bias, Q-scale (0.125 * log2e -> exp2-domain scores), bf16 store
#pragma unroll
  for (int ni = 0; ni < 6; ni++) {
    int col = bn * 192 + wn * 96 + ni * 16 + l15;
    int p = col >> 10;
    const float* bias = (p == 0) ? bq : (p == 1) ? bk : bv;
    float b = bias[col & 1023];
    float qscale = (p == 0) ? 0.125f * 1.44269504f : 1.0f;
    int h = (col >> 6) & 15, dd = col & 63;
    size_t base = ((size_t)(p * 16 + h) * 4096) * 64 + dd;
#pragma unroll
    for (int mi = 0; mi < 4; mi++) {
#pragma unroll
      for (int r = 0; r < 4; r++) {
        int s = bm * 256 + wm * 64 + mi * 16 + l4 * 4 + r;
        float v = (acc[mi][ni][r] + b) * qscale;
        qkv[base + (size_t)s * 64] = f2bf(v);
      }
    }
  }
}

// ------- banded flash attention: QBLK=128, 8 waves, swapped QK^T, dbuf -------
__global__ __launch_bounds__(512) void attn_local_kernel(
    const ushort* __restrict__ qkv, float* __restrict__ out) {
  __shared__ ushort lds[2][2][4096];  // [buf][0=K swz,1=V natural][64x64]
  const int bid = blockIdx.x;
  const int wid = (bid & 7) * 64 + (bid >> 3);   // 512 wgs: 2 heads per XCD
  const int h = wid >> 5;
  const int q0 = (wid & 31) << 7;                // 128-row q block
  const int t = threadIdx.x;
  const int lane = t & 63, w = t >> 6;
  const int l15 = lane & 15, l4 = lane >> 4;
  const int qw = q0 + w * 16;
  const int myq = qw + l15;

  const ushort* __restrict__ Q = qkv;
  const ushort* __restrict__ K = qkv + (size_t)16 * 4096 * 64;
  const ushort* __restrict__ V = K + (size_t)16 * 4096 * 64;

  s16x8 qf[2];
  {
    const ushort* qp = &Q[((size_t)h * 4096 + myq) * 64];
    qf[0] = *(const s16x8*)&qp[l4 * 8];
    qf[1] = *(const s16x8*)&qp[32 + l4 * 8];
  }

  U8 ones;
  {
    unsigned w1 = (l15 == 0) ? 0x3F803F80u : 0u;
    ones.u[0] = w1; ones.u[1] = w1; ones.u[2] = w1; ones.u[3] = w1;
  }

  f32x4 oacc[5];  // [0..3]: d-blocks; [4]: row-sum column (l15==0)
#pragma unroll
  for (int i = 0; i < 5; i++) oacc[i] = (f32x4)0.f;
  float mrow = -1e30f;

  const unsigned vtr0 = lds_addr(&lds[0][1][0]) +
      (unsigned)(l4 * 1024 + (l15 >> 2) * 128 + (l15 & 3) * 8);

  int kstart = q0 - 256; if (kstart < 0) kstart = 0;
  int kend = q0 + 384; if (kend > 4096) kend = 4096;

#define STAGE_KV(buf, kb)                                                      \
  do {                                                                         \
    const ushort* Kg = &K[((size_t)h * 4096 + (kb)) * 64];                     \
    const ushort* Vg = &V[((size_t)h * 4096 + (kb)) * 64];                     \
    int off = t * 8;                                                           \
    int row = off >> 6;                                                        \
    int c8 = (off >> 3) & 7;                                                   \
    async_copy16(&lds[buf][0][off], &Kg[row * 64 + ((c8 ^ (row & 7)) * 8)]);   \
    async_copy16(&lds[buf][1][off], &Vg[off]);                                 \
  } while (0)

  STAGE_KV(0, kstart);
  asm volatile("s_waitcnt vmcnt(0)");
  __builtin_amdgcn_s_barrier();

  for (int kb = kstart; kb < kend; kb += 64) {
    const int cur = ((kb - kstart) >> 6) & 1;
    if (kb + 64 < kend) {
      if (cur) STAGE_KV(0, kb + 64); else STAGE_KV(1, kb + 64);
    }
    bool active = (kb + 63 >= qw - 256) && (kb <= qw + 15 + 256);
    if (active) {
      const ushort* lK = &lds[cur][0][0];
      f32x4 st[4];
#pragma unroll
      for (int tt = 0; tt < 4; tt++) st[tt] = (f32x4)0.f;
      __builtin_amdgcn_s_setprio(1);
#pragma unroll
      for (int tt = 0; tt < 4; tt++) {
#pragma unroll
        for (int kc = 0; kc < 2; kc++) {
          int rowk = tt * 16 + l15;
          int g = (kc * 4 + l4) ^ (rowk & 7);
          s16x8 kf = *(const s16x8*)&lK[rowk * 64 + g * 8];
          st[tt] = __builtin_amdgcn_mfma_f32_16x16x32_bf16(kf, qf[kc], st[tt], 0, 0, 0);
        }
      }
      __builtin_amdgcn_s_setprio(0);
      float pe[4][4];
      const bool interior = (kb >= qw - 241) && (kb <= qw + 193);
      if (interior) {
#pragma unroll
        for (int tt = 0; tt < 4; tt++)
#pragma unroll
          for (int r = 0; r < 4; r++) pe[tt][r] = st[tt][r];
      } else {
#pragma unroll
        for (int tt = 0; tt < 4; tt++)
#pragma unroll
          for (int r = 0; r < 4; r++) {
            int key = kb + tt * 16 + l4 * 4 + r;
            pe[tt][r] = ((unsigned)(myq - key + 256) <= 512u) ? st[tt][r] : -3e38f;
          }
      }
      float m0 = fmaxf(fmaxf(pe[0][0], pe[0][1]), fmaxf(pe[0][2], pe[0][3]));
      float m1 = fmaxf(fmaxf(pe[1][0], pe[1][1]), fmaxf(pe[1][2], pe[1][3]));
      float m2 = fmaxf(fmaxf(pe[2][0], pe[2][1]), fmaxf(pe[2][2], pe[2][3]));
      float m3 = fmaxf(fmaxf(pe[3][0], pe[3][1]), fmaxf(pe[3][2], pe[3][3]));
      float rm = fmaxf(fmaxf(m0, m1), fmaxf(m2, m3));
      rm = fmaxf(rm, __shfl_xor(rm, 16));
      rm = fmaxf(rm, __shfl_xor(rm, 32));
      if (__any(rm > mrow + 8.0f)) {
        float mn = fmaxf(mrow, rm);
        float sc = __builtin_amdgcn_exp2f(mrow - mn);
        mrow = mn;
        float scr[4];
#pragma unroll
        for (int r = 0; r < 4; r++) scr[r] = __shfl(sc, l4 * 4 + r);
#pragma unroll
        for (int db = 0; db < 5; db++)
#pragma unroll
          for (int r = 0; r < 4; r++) oacc[db][r] *= scr[r];
      }
      unsigned pk[4][2];
#pragma unroll
      for (int tt = 0; tt < 4; tt++) {
        float e0 = __builtin_amdgcn_exp2f(pe[tt][0] - mrow);
        float e1 = __builtin_amdgcn_exp2f(pe[tt][1] - mrow);
        float e2 = __builtin_amdgcn_exp2f(pe[tt][2] - mrow);
        float e3 = __builtin_amdgcn_exp2f(pe[tt][3] - mrow);
        asm("v_cvt_pk_bf16_f32 %0, %1, %2" : "=v"(pk[tt][0]) : "v"(e0), "v"(e1));
        asm("v_cvt_pk_bf16_f32 %0, %1, %2" : "=v"(pk[tt][1]) : "v"(e2), "v"(e3));
      }

      const unsigned vtr = vtr0 + (unsigned)cur * 16384u;
#pragma unroll
      for (int c = 0; c < 2; c++) {
        u32x2 t00, t01, t10, t11, t20, t21, t30, t31;
        if (c == 0) {
          TRRD(t00, vtr, 0);    TRRD(t01, vtr, 512);
          TRRD(t10, vtr, 32);   TRRD(t11, vtr, 544);
          TRRD(t20, vtr, 64);   TRRD(t21, vtr, 576);
          TRRD(t30, vtr, 96);   TRRD(t31, vtr, 608);
        } else {
          TRRD(t00, vtr, 4096); TRRD(t01, vtr, 4608);
          TRRD(t10, vtr, 4128); TRRD(t11, vtr, 4640);
          TRRD(t20, vtr, 4160); TRRD(t21, vtr, 4672);
          TRRD(t30, vtr, 4192); TRRD(t31, vtr, 4704);
        }
        const int srcA = ((lane & 16) << 1) | l15;
        const int srcB = srcA + 16;
        const int tsel = (lane >> 5) & 1;
        unsigned x0 = (unsigned)__shfl((int)pk[2 * c][0], srcA);
        unsigned y0 = (unsigned)__shfl((int)pk[2 * c + 1][0], srcA);
        unsigned x1 = (unsigned)__shfl((int)pk[2 * c][1], srcA);
        unsigned y1 = (unsigned)__shfl((int)pk[2 * c + 1][1], srcA);
        unsigned x2 = (unsigned)__shfl((int)pk[2 * c][0], srcB);
        unsigned y2 = (unsigned)__shfl((int)pk[2 * c + 1][0], srcB);
        unsigned x3 = (unsigned)__shfl((int)pk[2 * c][1], srcB);
        unsigned y3 = (unsigned)__shfl((int)pk[2 * c + 1][1], srcB);
        U8 pf;
        pf.u[0] = tsel ? y0 : x0;
        pf.u[1] = tsel ? y1 : x1;
        pf.u[2] = tsel ? y2 : x2;
        pf.u[3] = tsel ? y3 : x3;
        asm volatile("s_waitcnt lgkmcnt(0)");
        __builtin_amdgcn_sched_barrier(0);
        U8 vf0, vf1, vf2, vf3;
        vf0.u[0] = t00[0]; vf0.u[1] = t00[1]; vf0.u[2] = t01[0]; vf0.u[3] = t01[1];
        vf1.u[0] = t10[0]; vf1.u[1] = t10[1]; vf1.u[2] = t11[0]; vf1.u[3] = t11[1];
        vf2.u[0] = t20[0]; vf2.u[1] = t20[1]; vf2.u[2] = t21[0]; vf2.u[3] = t21[1];
        vf3.u[0] = t30[0]; vf3.u[1] = t30[1]; vf3.u[2] = t31[0]; vf3.u[3] = t31[1];
        __builtin_amdgcn_s_setprio(1);
        oacc[0] = __builtin_amdgcn_mfma_f32_16x16x32_bf16(pf.v, vf0.v, oacc[0], 0, 0, 0);
        oacc[1] = __builtin_amdgcn_mfma_f32_16x16x32_bf16(pf.v, vf1.v, oacc[1], 0, 0, 0);
        oacc[2] = __builtin_amdgcn_mfma_f32_16x16x32_bf16(pf.v, vf2.v, oacc[2], 0, 0, 0);
        oacc[3] = __builtin_amdgcn_mfma_f32_16x16x32_bf16(pf.v, vf3.v, oacc[3], 0, 0, 0);
        oacc[4] = __builtin_amdgcn_mfma_f32_16x16x32_bf16(pf.v, ones.v, oacc[4], 0, 0, 0);
        __builtin_amdgcn_s_setprio(0);
      }
    }
    asm volatile("s_waitcnt vmcnt(0)");
    __builtin_amdgcn_s_barrier();
  }
#undef STAGE_KV
  float linv[4];
#pragma unroll
  for (int r = 0; r < 4; r++) linv[r] = 1.0f / __shfl(oacc[4][r], lane & 48);
#pragma unroll
  for (int db = 0; db < 4; db++)
#pragma unroll
    for (int r = 0; r < 4; r++) {
      int s = qw + l4 * 4 + r;
      out[(size_t)s * 1024 + h * 64 + db * 16 + l15] = oacc[db][r] * linv[r];
    }
}

extern "C" void kernel_launch(void* const* d_in, const int* in_sizes, int n_in,
                              void* d_out, int out_size, void* d_ws, size_t ws_size,
                              hipStream_t stream) {
  const float* x  = (const float*)d_in[0];
  const float* Wq = (const float*)d_in[1];
  const float* bq = (const float*)d_in[2];
  const float* Wk = (const float*)d_in[3];
  const float* bk = (const float*)d_in[4];
  const float* Wv = (const float*)d_in[5];
  const float* bv = (const float*)d_in[6];

  ushort* qkv = (ushort*)d_ws;                                   // 24 MB
  ushort* xs  = (ushort*)((char*)d_ws + (size_t)25165824);       // 8 MB
  ushort* wsb = xs + (size_t)4096 * 1024;                        // 6 MB
  float* out = (float*)d_out;

  convert_kernel<<<3584, 256, 0, stream>>>(x, Wq, Wk, Wv, xs, wsb);
  qkv_gemm_kernel<<<256, 512, 0, stream>>>(xs, wsb, bq, bk, bv, qkv);
  attn_local_kernel<<<512, 512, 0, stream>>>(qkv, out);
}

// Round 8
// 67.284 us; speedup vs baseline: 1.7390x; 1.0286x over previous
//
#include <hip/hip_runtime.h>
#include <hip/hip_bf16.h>

typedef __attribute__((ext_vector_type(4))) float f32x4;
typedef __attribute__((ext_vector_type(16))) float f32x16;
typedef __attribute__((ext_vector_type(8))) short s16x8;
typedef __attribute__((ext_vector_type(4))) float float4_t;
typedef __attribute__((ext_vector_type(2))) unsigned int u32x2;

union U8 { s16x8 v; unsigned u[4]; };

__device__ __forceinline__ ushort f2bf(float f) {
  union { float f; unsigned u; } v; v.f = f;
  unsigned r = v.u + 0x7fffu + ((v.u >> 16) & 1u);
  return (ushort)(r >> 16);
}

__device__ __forceinline__ void async_copy16(ushort* lds, const ushort* g) {
  __builtin_amdgcn_global_load_lds(
      (const __attribute__((address_space(1))) unsigned int*)g,
      (__attribute__((address_space(3))) unsigned int*)lds, 16, 0, 0);
}

__device__ __forceinline__ unsigned lds_addr(const void* p) {
  return (unsigned)(unsigned long long)(__attribute__((address_space(3))) const void*)p;
}

#define TRRD(dst, addr, off_lit) \
  asm volatile("ds_read_b64_tr_b16 %0, %1 offset:" #off_lit : "=v"(dst) : "v"(addr))

// ---------- merged f32 -> bf16 pre-swizzled panel conversion ----------
__global__ __launch_bounds__(256) void convert_kernel(
    const float* __restrict__ x, const float* __restrict__ Wq,
    const float* __restrict__ Wk, const float* __restrict__ Wv,
    ushort* __restrict__ xs, ushort* __restrict__ ws) {
  int b = blockIdx.x;
  if (b < 2048) {
    int c = b * 256 + threadIdx.x;
    int kc = c & 127;
    int m = c >> 7;
    const float4_t* s = (const float4_t*)&x[(size_t)m * 1024 + kc * 8];
    float4_t a0 = s[0], a1 = s[1];
    s16x8 v;
    v[0] = (short)f2bf(a0[0]); v[1] = (short)f2bf(a0[1]);
    v[2] = (short)f2bf(a0[2]); v[3] = (short)f2bf(a0[3]);
    v[4] = (short)f2bf(a1[0]); v[5] = (short)f2bf(a1[1]);
    v[6] = (short)f2bf(a1[2]); v[7] = (short)f2bf(a1[3]);
    int tm = m >> 7, tk = kc >> 3, r = m & 127, c8 = kc & 7;
    *(s16x8*)&xs[((size_t)(tm * 16 + tk) * 128 + r) * 64 + ((c8 ^ (r & 7)) * 8)] = v;
  } else {
    int c = (b - 2048) * 256 + threadIdx.x;
    int kc = c & 127;
    int n = c >> 7;
    int p = n >> 10, nW = n & 1023;
    const float* __restrict__ W = (p == 0) ? Wq : (p == 1) ? Wk : Wv;
    const float4_t* s = (const float4_t*)&W[(size_t)nW * 1024 + kc * 8];
    float4_t a0 = s[0], a1 = s[1];
    s16x8 v;
    v[0] = (short)f2bf(a0[0]); v[1] = (short)f2bf(a0[1]);
    v[2] = (short)f2bf(a0[2]); v[3] = (short)f2bf(a0[3]);
    v[4] = (short)f2bf(a1[0]); v[5] = (short)f2bf(a1[1]);
    v[6] = (short)f2bf(a1[2]); v[7] = (short)f2bf(a1[3]);
    unsigned tn3 = (unsigned)n / 192u;
    unsigned r = (unsigned)n - tn3 * 192u;
    int tk = kc >> 3, c8 = kc & 7;
    *(s16x8*)&ws[((size_t)(tn3 * 16 + tk) * 192 + r) * 64 + ((c8 ^ (r & 7)) * 8)] = v;
  }
}

// ---------------- fused QKV GEMM: 256x192 tile, BK=64, 8 waves, dbuf pipeline ----
__global__ __launch_bounds__(512, 2) void qkv_gemm_kernel(
    const ushort* __restrict__ xs, const ushort* __restrict__ wsb,
    const float* __restrict__ bq, const float* __restrict__ bk,
    const float* __restrict__ bv, ushort* __restrict__ qkv) {
  __shared__ ushort lA[2][16384];
  __shared__ ushort lB[2][12288];
  const int t = threadIdx.x;
  const int lane = t & 63, w = t >> 6;
  const int wm = w >> 1, wn = w & 1;
  const int l15 = lane & 15, l4 = lane >> 4;
  const int phys = blockIdx.x;
  const int swz = (phys & 7) * 32 + (phys >> 3);
  const int xcd = swz >> 5, jj = swz & 31;
  const int bm = (xcd >> 1) * 4 + (jj >> 3);
  const int bn = (xcd & 1) * 8 + (jj & 7);

  const ushort* Apan = xs + (size_t)(2 * bm) * 16 * 8192;
  const ushort* Bpan = wsb + (size_t)bn * 16 * 12288;

  f32x4 acc[4][6];
#pragma unroll
  for (int i = 0; i < 4; i++)
#pragma unroll
    for (int j = 0; j < 6; j++) acc[i][j] = (f32x4)0.f;

#define STAGE_A(buf, kt)                                                        \
  do {                                                                          \
    const ushort* s0 = Apan + (size_t)(kt) * 8192;                              \
    const ushort* s1 = Apan + (size_t)(16 + (kt)) * 8192;                       \
    async_copy16(&lA[buf][t * 8], s0 + t * 8);                                  \
    async_copy16(&lA[buf][(t + 512) * 8], s0 + (t + 512) * 8);                  \
    async_copy16(&lA[buf][8192 + t * 8], s1 + t * 8);                           \
    async_copy16(&lA[buf][8192 + (t + 512) * 8], s1 + (t + 512) * 8);           \
  } while (0)
#define STAGE_B(buf, kt)                                                        \
  do {                                                                          \
    const ushort* s2 = Bpan + (size_t)(kt) * 12288;                             \
    async_copy16(&lB[buf][t * 8], s2 + t * 8);                                  \
    async_copy16(&lB[buf][(t + 512) * 8], s2 + (t + 512) * 8);                  \
    async_copy16(&lB[buf][(t + 1024) * 8], s2 + (t + 1024) * 8);                \
  } while (0)

  STAGE_A(0, 0);
  STAGE_B(0, 0);
  asm volatile("s_waitcnt vmcnt(0)");
  __builtin_amdgcn_s_barrier();

  for (int kt = 0; kt < 16; ++kt) {
    const int cur = kt & 1;
    s16x8 af[4], bfr[6];
#pragma unroll
    for (int mi = 0; mi < 4; mi++) {
      int ra = wm * 64 + mi * 16 + l15;
      int g = l4 ^ (ra & 7);
      af[mi] = *(const s16x8*)&lA[cur][ra * 64 + g * 8];
    }
#pragma unroll
    for (int ni = 0; ni < 6; ni++) {
      int rb = wn * 96 + ni * 16 + l15;
      int g = l4 ^ (rb & 7);
      bfr[ni] = *(const s16x8*)&lB[cur][rb * 64 + g * 8];
    }
    if (kt + 1 < 16) {
      STAGE_A(cur ^ 1, kt + 1);
      STAGE_B(cur ^ 1, kt + 1);
    }
    __builtin_amdgcn_s_barrier();
    asm volatile("s_waitcnt lgkmcnt(0)");
    __builtin_amdgcn_sched_barrier(0);
    __builtin_amdgcn_s_setprio(1);
#pragma unroll
    for (int mi = 0; mi < 4; mi++)
#pragma unroll
      for (int ni = 0; ni < 6; ni++)
        acc[mi][ni] = __builtin_amdgcn_mfma_f32_16x16x32_bf16(af[mi], bfr[ni], acc[mi][ni], 0, 0, 0);
    __builtin_amdgcn_s_setprio(0);
    __builtin_amdgcn_s_barrier();
#pragma unroll
    for (int mi = 0; mi < 4; mi++) {
      int ra = wm * 64 + mi * 16 + l15;
      int g = (4 + l4) ^ (ra & 7);
      af[mi] = *(const s16x8*)&lA[cur][ra * 64 + g * 8];
    }
#pragma unroll
    for (int ni = 0; ni < 6; ni++) {
      int rb = wn * 96 + ni * 16 + l15;
      int g = (4 + l4) ^ (rb & 7);
      bfr[ni] = *(const s16x8*)&lB[cur][rb * 64 + g * 8];
    }
    __builtin_amdgcn_s_barrier();
    asm volatile("s_waitcnt lgkmcnt(0)");
    __builtin_amdgcn_sched_barrier(0);
    __builtin_amdgcn_s_setprio(1);
#pragma unroll
    for (int mi = 0; mi < 4; mi++)
#pragma unroll
      for (int ni = 0; ni < 6; ni++)
        acc[mi][ni] = __builtin_amdgcn_mfma_f32_16x16x32_bf16(af[mi], bfr[ni], acc[mi][ni], 0, 0, 0);
    __builtin_amdgcn_s_setprio(0);
    asm volatile("s_waitcnt vmcnt(0)");
    __builtin_amdgcn_s_barrier();
  }
#undef STAGE_A
#undef STAGE_B

#pragma unroll
  for (int ni = 0; ni < 6; ni++) {
    int col = bn * 192 + wn * 96 + ni * 16 + l15;
    int p = col >> 10;
    const float* bias = (p == 0) ? bq : (p == 1) ? bk : bv;
    float b = bias[col & 1023];
    float qscale = (p == 0) ? 0.125f * 1.44269504f : 1.0f;
    int h = (col >> 6) & 15, dd = col & 63;
    size_t base = ((size_t)(p * 16 + h) * 4096) * 64 + dd;
#pragma unroll
    for (int mi = 0; mi < 4; mi++) {
#pragma unroll
      for (int r = 0; r < 4; r++) {
        int s = bm * 256 + wm * 64 + mi * 16 + l4 * 4 + r;
        float v = (acc[mi][ni][r] + b) * qscale;
        qkv[base + (size_t)s * 64] = f2bf(v);
      }
    }
  }
}

// ------- banded flash attention v2: 32x32 MFMA, QBLK=128, 4 waves x 32 q -------
__global__ __launch_bounds__(256) void attn_local_kernel(
    const ushort* __restrict__ qkv, float* __restrict__ out) {
  __shared__ ushort lds[2][2][4096];  // [buf][0=K swz,1=V natural][64x64]
  const int bid = blockIdx.x;
  const int wid = (bid & 7) * 64 + (bid >> 3);   // 512 wgs: 2 heads per XCD
  const int hd = wid >> 5;
  const int q0 = (wid & 31) << 7;                // 128-row q block
  const int t = threadIdx.x;
  const int lane = t & 63, w = t >> 6;
  const int l15 = lane & 15, l31 = lane & 31;
  const int b4 = (lane >> 4) & 1, hf = lane >> 5;
  const int qw = q0 + w * 32;
  const int myq = qw + l31;

  const ushort* __restrict__ Q = qkv;
  const ushort* __restrict__ K = qkv + (size_t)16 * 4096 * 64;
  const ushort* __restrict__ V = K + (size_t)16 * 4096 * 64;

  // Q as 32x32 B-operand: col=l31 -> q, k-elems d = 16*kc + 8*hf + j
  s16x8 qf[4];
  {
    const ushort* qp = &Q[((size_t)hd * 4096 + myq) * 64];
#pragma unroll
    for (int kc = 0; kc < 4; kc++) qf[kc] = *(const s16x8*)&qp[16 * kc + 8 * hf];
  }

  U8 ones;
  {
    unsigned w1 = (l31 == 0) ? 0x3F803F80u : 0u;
    ones.u[0] = w1; ones.u[1] = w1; ones.u[2] = w1; ones.u[3] = w1;
  }

  f32x16 oa0 = (f32x16)0.f, oa1 = (f32x16)0.f, oden = (f32x16)0.f;
  float mrow = -1e30f;

  // tr-read base: group (hf,b4) covers keys 8hf..+3(+512 for +4), cols 16*b4..+15
  const unsigned vtr0 = lds_addr(&lds[0][1][0]) +
      (unsigned)(hf * 1024 + (l15 >> 2) * 128 + b4 * 32 + (l15 & 3) * 8);

  int kstart = q0 - 256; if (kstart < 0) kstart = 0;
  int kend = q0 + 384; if (kend > 4096) kend = 4096;

#define STAGE_KV(buf, kb)                                                      \
  do {                                                                         \
    const ushort* Kg = &K[((size_t)hd * 4096 + (kb)) * 64];                    \
    const ushort* Vg = &V[((size_t)hd * 4096 + (kb)) * 64];                    \
    _Pragma("unroll") for (int i = 0; i < 2; i++) {                            \
      int off = i * 2048 + t * 8;                                              \
      int row = off >> 6;                                                      \
      int c8s = (off >> 3) & 7;                                                \
      async_copy16(&lds[buf][0][off], &Kg[row * 64 + ((c8s ^ (row & 7)) * 8)]);\
      async_copy16(&lds[buf][1][off], &Vg[off]);                               \
    }                                                                          \
  } while (0)

  STAGE_KV(0, kstart);
  asm volatile("s_waitcnt vmcnt(0)");
  __builtin_amdgcn_s_barrier();

  for (int kb = kstart; kb < kend; kb += 64) {
    const int cur = ((kb - kstart) >> 6) & 1;
    if (kb + 64 < kend) {
      if (cur) STAGE_KV(0, kb + 64); else STAGE_KV(1, kb + 64);
    }
    bool active = (kb + 63 >= qw - 256) && (kb <= qw + 31 + 256);
    if (active) {
      const ushort* lK = &lds[cur][0][0];
      f32x16 st0 = (f32x16)0.f, st1 = (f32x16)0.f;
      __builtin_amdgcn_s_setprio(1);
#pragma unroll
      for (int kc = 0; kc < 4; kc++) {
        int c8 = 2 * kc + hf;
        int r0 = l31;
        s16x8 kf0 = *(const s16x8*)&lK[r0 * 64 + ((c8 ^ (r0 & 7)) * 8)];
        st0 = __builtin_amdgcn_mfma_f32_32x32x16_bf16(kf0, qf[kc], st0, 0, 0, 0);
        int r1 = 32 + l31;
        s16x8 kf1 = *(const s16x8*)&lK[r1 * 64 + ((c8 ^ (r1 & 7)) * 8)];
        st1 = __builtin_amdgcn_mfma_f32_32x32x16_bf16(kf1, qf[kc], st1, 0, 0, 0);
      }
      __builtin_amdgcn_s_setprio(0);
      // band mask (rows = keys, col = own q)
      const bool interior = (kb >= qw - 225) && (kb <= qw + 193);
      if (!interior) {
        int base0 = myq - kb - 4 * hf + 256;  // valid iff 0 <= base0-keyoff <= 512
#pragma unroll
        for (int r = 0; r < 16; r++) {
          int ko = (r & 3) + 8 * (r >> 2);
          if (!((unsigned)(base0 - ko) <= 512u)) st0[r] = -3e38f;
          if (!((unsigned)(base0 - 32 - ko) <= 512u)) st1[r] = -3e38f;
        }
      }
      // row max over 32 in-lane values + pair lane (l ^ 32)
      float rm;
      {
        float a = fmaxf(fmaxf(st0[0], st0[1]), fmaxf(st0[2], st0[3]));
        float b = fmaxf(fmaxf(st0[4], st0[5]), fmaxf(st0[6], st0[7]));
        float c = fmaxf(fmaxf(st0[8], st0[9]), fmaxf(st0[10], st0[11]));
        float d = fmaxf(fmaxf(st0[12], st0[13]), fmaxf(st0[14], st0[15]));
        float e = fmaxf(fmaxf(st1[0], st1[1]), fmaxf(st1[2], st1[3]));
        float f = fmaxf(fmaxf(st1[4], st1[5]), fmaxf(st1[6], st1[7]));
        float g = fmaxf(fmaxf(st1[8], st1[9]), fmaxf(st1[10], st1[11]));
        float h2 = fmaxf(fmaxf(st1[12], st1[13]), fmaxf(st1[14], st1[15]));
        rm = fmaxf(fmaxf(fmaxf(a, b), fmaxf(c, d)), fmaxf(fmaxf(e, f), fmaxf(g, h2)));
      }
      rm = fmaxf(rm, __shfl_xor(rm, 32));
      // defer-max rescale (O rows are q-rows -> per-row scale via shfl)
      if (__any(rm > mrow + 8.0f)) {
        float mn = fmaxf(mrow, rm);
        float sc = __builtin_amdgcn_exp2f(mrow - mn);
        mrow = mn;
        int srcB = (lane & 32); srcB += srcB >> 3;  // lane&32 + 4*hf
#pragma unroll
        for (int r = 0; r < 16; r++) {
          float scr = __shfl(sc, srcB + (r & 3) + 8 * (r >> 2));
          oa0[r] *= scr; oa1[r] *= scr; oden[r] *= scr;
        }
      }
      const unsigned vtr = vtr0 + (unsigned)cur * 16384u;
      // PV per 16-key chunk: exp2+pack -> 2 permlane swaps -> tr-read V -> 3 MFMA
#define PVC(STV, RB, O0, O1, O2, O3)                                           \
  do {                                                                         \
    u32x2 ta, tb, tc2, td;                                                     \
    TRRD(ta, vtr, O0); TRRD(tb, vtr, O1); TRRD(tc2, vtr, O2); TRRD(td, vtr, O3);\
    float e0 = __builtin_amdgcn_exp2f(STV[RB + 0] - mrow);                     \
    float e1 = __builtin_amdgcn_exp2f(STV[RB + 1] - mrow);                     \
    float e2 = __builtin_amdgcn_exp2f(STV[RB + 2] - mrow);                     \
    float e3 = __builtin_amdgcn_exp2f(STV[RB + 3] - mrow);                     \
    float e4 = __builtin_amdgcn_exp2f(STV[RB + 4] - mrow);                     \
    float e5 = __builtin_amdgcn_exp2f(STV[RB + 5] - mrow);                     \
    float e6 = __builtin_amdgcn_exp2f(STV[RB + 6] - mrow);                     \
    float e7 = __builtin_amdgcn_exp2f(STV[RB + 7] - mrow);                     \
    unsigned a0, a1, b0, b1;                                                   \
    asm("v_cvt_pk_bf16_f32 %0, %1, %2" : "=v"(a0) : "v"(e0), "v"(e1));         \
    asm("v_cvt_pk_bf16_f32 %0, %1, %2" : "=v"(a1) : "v"(e2), "v"(e3));         \
    asm("v_cvt_pk_bf16_f32 %0, %1, %2" : "=v"(b0) : "v"(e4), "v"(e5));         \
    asm("v_cvt_pk_bf16_f32 %0, %1, %2" : "=v"(b1) : "v"(e6), "v"(e7));         \
    asm volatile("v_permlane32_swap_b32 %0, %1" : "+v"(a0), "+v"(b0));         \
    asm volatile("v_permlane32_swap_b32 %0, %1" : "+v"(a1), "+v"(b1));         \
    U8 pa; pa.u[0] = a0; pa.u[1] = a1; pa.u[2] = b0; pa.u[3] = b1;             \
    asm volatile("s_waitcnt lgkmcnt(0)");                                      \
    __builtin_amdgcn_sched_barrier(0);                                         \
    U8 vf0, vf1;                                                               \
    vf0.u[0] = ta[0]; vf0.u[1] = ta[1]; vf0.u[2] = tb[0]; vf0.u[3] = tb[1];    \
    vf1.u[0] = tc2[0]; vf1.u[1] = tc2[1]; vf1.u[2] = td[0]; vf1.u[3] = td[1];  \
    __builtin_amdgcn_s_setprio(1);                                             \
    oa0 = __builtin_amdgcn_mfma_f32_32x32x16_bf16(pa.v, vf0.v, oa0, 0, 0, 0);  \
    oa1 = __builtin_amdgcn_mfma_f32_32x32x16_bf16(pa.v, vf1.v, oa1, 0, 0, 0);  \
    oden = __builtin_amdgcn_mfma_f32_32x32x16_bf16(pa.v, ones.v, oden, 0, 0, 0);\
    __builtin_amdgcn_s_setprio(0);                                             \
  } while (0)
      PVC(st0, 0, 0, 512, 64, 576);
      PVC(st0, 8, 2048, 2560, 2112, 2624);
      PVC(st1, 0, 4096, 4608, 4160, 4672);
      PVC(st1, 8, 6144, 6656, 6208, 6720);
#undef PVC
    }
    asm volatile("s_waitcnt vmcnt(0)");
    __builtin_amdgcn_s_barrier();
  }
#undef STAGE_KV
  // epilogue: per-q denominator lives at col-0 lane of own half
#pragma unroll
  for (int r = 0; r < 16; r++) {
    float den = __shfl(oden[r], lane & 32);
    float linv = 1.0f / den;
    int s = qw + (r & 3) + 8 * (r >> 2) + 4 * hf;
    out[(size_t)s * 1024 + hd * 64 + l31] = oa0[r] * linv;
    out[(size_t)s * 1024 + hd * 64 + 32 + l31] = oa1[r] * linv;
  }
}

extern "C" void kernel_launch(void* const* d_in, const int* in_sizes, int n_in,
                              void* d_out, int out_size, void* d_ws, size_t ws_size,
                              hipStream_t stream) {
  const float* x  = (const float*)d_in[0];
  const float* Wq = (const float*)d_in[1];
  const float* bq = (const float*)d_in[2];
  const float* Wk = (const float*)d_in[3];
  const float* bk = (const float*)d_in[4];
  const float* Wv = (const float*)d_in[5];
  const float* bv = (const float*)d_in[6];

  ushort* qkv = (ushort*)d_ws;                                   // 24 MB
  ushort* xs  = (ushort*)((char*)d_ws + (size_t)25165824);       // 8 MB
  ushort* wsb = xs + (size_t)4096 * 1024;                        // 6 MB
  float* out = (float*)d_out;

  convert_kernel<<<3584, 256, 0, stream>>>(x, Wq, Wk, Wv, xs, wsb);
  qkv_gemm_kernel<<<256, 512, 0, stream>>>(xs, wsb, bq, bk, bv, qkv);
  attn_local_kernel<<<512, 256, 0, stream>>>(qkv, out);
}

// Round 9
// 63.595 us; speedup vs baseline: 1.8399x; 1.0580x over previous
//
#include <hip/hip_runtime.h>
#include <hip/hip_bf16.h>

typedef __attribute__((ext_vector_type(4))) float f32x4;
typedef __attribute__((ext_vector_type(16))) float f32x16;
typedef __attribute__((ext_vector_type(8))) short s16x8;
typedef __attribute__((ext_vector_type(4))) float float4_t;
typedef __attribute__((ext_vector_type(2))) unsigned int u32x2;

union U8 { s16x8 v; unsigned u[4]; };

__device__ __forceinline__ ushort f2bf(float f) {
  union { float f; unsigned u; } v; v.f = f;
  unsigned r = v.u + 0x7fffu + ((v.u >> 16) & 1u);
  return (ushort)(r >> 16);
}

__device__ __forceinline__ void async_copy16(ushort* lds, const ushort* g) {
  __builtin_amdgcn_global_load_lds(
      (const __attribute__((address_space(1))) unsigned int*)g,
      (__attribute__((address_space(3))) unsigned int*)lds, 16, 0, 0);
}

__device__ __forceinline__ unsigned lds_addr(const void* p) {
  return (unsigned)(unsigned long long)(__attribute__((address_space(3))) const void*)p;
}

#define TRRD(dst, addr, off_lit) \
  asm volatile("ds_read_b64_tr_b16 %0, %1 offset:" #off_lit : "=v"(dst) : "v"(addr))

// ---------- merged f32 -> bf16 pre-swizzled panel conversion ----------
__global__ __launch_bounds__(256) void convert_kernel(
    const float* __restrict__ x, const float* __restrict__ Wq,
    const float* __restrict__ Wk, const float* __restrict__ Wv,
    ushort* __restrict__ xs, ushort* __restrict__ ws) {
  int b = blockIdx.x;
  if (b < 2048) {
    int c = b * 256 + threadIdx.x;
    int kc = c & 127;
    int m = c >> 7;
    const float4_t* s = (const float4_t*)&x[(size_t)m * 1024 + kc * 8];
    float4_t a0 = s[0], a1 = s[1];
    s16x8 v;
    v[0] = (short)f2bf(a0[0]); v[1] = (short)f2bf(a0[1]);
    v[2] = (short)f2bf(a0[2]); v[3] = (short)f2bf(a0[3]);
    v[4] = (short)f2bf(a1[0]); v[5] = (short)f2bf(a1[1]);
    v[6] = (short)f2bf(a1[2]); v[7] = (short)f2bf(a1[3]);
    int tm = m >> 7, tk = kc >> 3, r = m & 127, c8 = kc & 7;
    *(s16x8*)&xs[((size_t)(tm * 16 + tk) * 128 + r) * 64 + ((c8 ^ (r & 7)) * 8)] = v;
  } else {
    int c = (b - 2048) * 256 + threadIdx.x;
    int kc = c & 127;
    int n = c >> 7;
    int p = n >> 10, nW = n & 1023;
    const float* __restrict__ W = (p == 0) ? Wq : (p == 1) ? Wk : Wv;
    const float4_t* s = (const float4_t*)&W[(size_t)nW * 1024 + kc * 8];
    float4_t a0 = s[0], a1 = s[1];
    s16x8 v;
    v[0] = (short)f2bf(a0[0]); v[1] = (short)f2bf(a0[1]);
    v[2] = (short)f2bf(a0[2]); v[3] = (short)f2bf(a0[3]);
    v[4] = (short)f2bf(a1[0]); v[5] = (short)f2bf(a1[1]);
    v[6] = (short)f2bf(a1[2]); v[7] = (short)f2bf(a1[3]);
    unsigned tn3 = (unsigned)n / 192u;
    unsigned r = (unsigned)n - tn3 * 192u;
    int tk = kc >> 3, c8 = kc & 7;
    *(s16x8*)&ws[((size_t)(tn3 * 16 + tk) * 192 + r) * 64 + ((c8 ^ (r & 7)) * 8)] = v;
  }
}

// -------- fused QKV GEMM: 256x192 tile, BK=64, 8 waves, dbuf, 1 barrier/kt ----
__global__ __launch_bounds__(512, 2) void qkv_gemm_kernel(
    const ushort* __restrict__ xs, const ushort* __restrict__ wsb,
    const float* __restrict__ bq, const float* __restrict__ bk,
    const float* __restrict__ bv, ushort* __restrict__ qkv) {
  __shared__ ushort lA[2][16384];
  __shared__ ushort lB[2][12288];
  const int t = threadIdx.x;
  const int lane = t & 63, w = t >> 6;
  const int wm = w >> 1, wn = w & 1;
  const int l15 = lane & 15, l4 = lane >> 4;
  const int phys = blockIdx.x;
  const int swz = (phys & 7) * 32 + (phys >> 3);
  const int xcd = swz >> 5, jj = swz & 31;
  const int bm = (xcd >> 1) * 4 + (jj >> 3);
  const int bn = (xcd & 1) * 8 + (jj & 7);

  const ushort* Apan = xs + (size_t)(2 * bm) * 16 * 8192;
  const ushort* Bpan = wsb + (size_t)bn * 16 * 12288;

  f32x4 acc[4][6];
#pragma unroll
  for (int i = 0; i < 4; i++)
#pragma unroll
    for (int j = 0; j < 6; j++) acc[i][j] = (f32x4)0.f;

#define STAGE_A(buf, kt)                                                        \
  do {                                                                          \
    const ushort* s0 = Apan + (size_t)(kt) * 8192;                              \
    const ushort* s1 = Apan + (size_t)(16 + (kt)) * 8192;                       \
    async_copy16(&lA[buf][t * 8], s0 + t * 8);                                  \
    async_copy16(&lA[buf][(t + 512) * 8], s0 + (t + 512) * 8);                  \
    async_copy16(&lA[buf][8192 + t * 8], s1 + t * 8);                           \
    async_copy16(&lA[buf][8192 + (t + 512) * 8], s1 + (t + 512) * 8);           \
  } while (0)
#define STAGE_B(buf, kt)                                                        \
  do {                                                                          \
    const ushort* s2 = Bpan + (size_t)(kt) * 12288;                             \
    async_copy16(&lB[buf][t * 8], s2 + t * 8);                                  \
    async_copy16(&lB[buf][(t + 512) * 8], s2 + (t + 512) * 8);                  \
    async_copy16(&lB[buf][(t + 1024) * 8], s2 + (t + 1024) * 8);                \
  } while (0)

  STAGE_A(0, 0);
  STAGE_B(0, 0);
  asm volatile("s_waitcnt vmcnt(0)");
  __builtin_amdgcn_s_barrier();

  for (int kt = 0; kt < 16; ++kt) {
    const int cur = kt & 1;
    // ---- phase 0 (kk = 0): reads + STAGE_A(kt+1), no extra barriers ----
    s16x8 af[4], bfr[6];
#pragma unroll
    for (int mi = 0; mi < 4; mi++) {
      int ra = wm * 64 + mi * 16 + l15;
      int g = l4 ^ (ra & 7);
      af[mi] = *(const s16x8*)&lA[cur][ra * 64 + g * 8];
    }
#pragma unroll
    for (int ni = 0; ni < 6; ni++) {
      int rb = wn * 96 + ni * 16 + l15;
      int g = l4 ^ (rb & 7);
      bfr[ni] = *(const s16x8*)&lB[cur][rb * 64 + g * 8];
    }
    if (kt + 1 < 16) STAGE_A(cur ^ 1, kt + 1);
    asm volatile("s_waitcnt lgkmcnt(0)");
    __builtin_amdgcn_sched_barrier(0);
    __builtin_amdgcn_s_setprio(1);
#pragma unroll
    for (int mi = 0; mi < 4; mi++)
#pragma unroll
      for (int ni = 0; ni < 6; ni++)
        acc[mi][ni] = __builtin_amdgcn_mfma_f32_16x16x32_bf16(af[mi], bfr[ni], acc[mi][ni], 0, 0, 0);
    __builtin_amdgcn_s_setprio(0);
    // ---- phase 1 (kk = 1): reads + STAGE_B(kt+1) ----
#pragma unroll
    for (int mi = 0; mi < 4; mi++) {
      int ra = wm * 64 + mi * 16 + l15;
      int g = (4 + l4) ^ (ra & 7);
      af[mi] = *(const s16x8*)&lA[cur][ra * 64 + g * 8];
    }
#pragma unroll
    for (int ni = 0; ni < 6; ni++) {
      int rb = wn * 96 + ni * 16 + l15;
      int g = (4 + l4) ^ (rb & 7);
      bfr[ni] = *(const s16x8*)&lB[cur][rb * 64 + g * 8];
    }
    if (kt + 1 < 16) STAGE_B(cur ^ 1, kt + 1);
    asm volatile("s_waitcnt lgkmcnt(0)");
    __builtin_amdgcn_sched_barrier(0);
    __builtin_amdgcn_s_setprio(1);
#pragma unroll
    for (int mi = 0; mi < 4; mi++)
#pragma unroll
      for (int ni = 0; ni < 6; ni++)
        acc[mi][ni] = __builtin_amdgcn_mfma_f32_16x16x32_bf16(af[mi], bfr[ni], acc[mi][ni], 0, 0, 0);
    __builtin_amdgcn_s_setprio(0);
    asm volatile("s_waitcnt vmcnt(0)");
    __builtin_amdgcn_s_barrier();
  }
#undef STAGE_A
#undef STAGE_B

#pragma unroll
  for (int ni = 0; ni < 6; ni++) {
    int col = bn * 192 + wn * 96 + ni * 16 + l15;
    int p = col >> 10;
    const float* bias = (p == 0) ? bq : (p == 1) ? bk : bv;
    float b = bias[col & 1023];
    float qscale = (p == 0) ? 0.125f * 1.44269504f : 1.0f;
    int h = (col >> 6) & 15, dd = col & 63;
    size_t base = ((size_t)(p * 16 + h) * 4096) * 64 + dd;
#pragma unroll
    for (int mi = 0; mi < 4; mi++) {
#pragma unroll
      for (int r = 0; r < 4; r++) {
        int s = bm * 256 + wm * 64 + mi * 16 + l4 * 4 + r;
        float v = (acc[mi][ni][r] + b) * qscale;
        qkv[base + (size_t)s * 64] = f2bf(v);
      }
    }
  }
}

// ------- banded flash attention v3: 32x32 MFMA, hoisted tr-reads, counted lgkm --
__global__ __launch_bounds__(256) void attn_local_kernel(
    const ushort* __restrict__ qkv, float* __restrict__ out) {
  __shared__ ushort lds[2][2][4096];  // [buf][0=K swz,1=V natural][64x64]
  const int bid = blockIdx.x;
  const int wid = (bid & 7) * 64 + (bid >> 3);
  const int hd = wid >> 5;
  const int q0 = (wid & 31) << 7;
  const int t = threadIdx.x;
  const int lane = t & 63, w = t >> 6;
  const int l15 = lane & 15, l31 = lane & 31;
  const int b4 = (lane >> 4) & 1, hf = lane >> 5;
  const int qw = q0 + w * 32;
  const int myq = qw + l31;

  const ushort* __restrict__ Q = qkv;
  const ushort* __restrict__ K = qkv + (size_t)16 * 4096 * 64;
  const ushort* __restrict__ V = K + (size_t)16 * 4096 * 64;

  s16x8 qf[4];
  {
    const ushort* qp = &Q[((size_t)hd * 4096 + myq) * 64];
#pragma unroll
    for (int kc = 0; kc < 4; kc++) qf[kc] = *(const s16x8*)&qp[16 * kc + 8 * hf];
  }

  U8 ones;
  {
    unsigned w1 = (l31 == 0) ? 0x3F803F80u : 0u;
    ones.u[0] = w1; ones.u[1] = w1; ones.u[2] = w1; ones.u[3] = w1;
  }

  f32x16 oa0 = (f32x16)0.f, oa1 = (f32x16)0.f, oden = (f32x16)0.f;
  float mrow = -1e30f;

  const unsigned vtr0 = lds_addr(&lds[0][1][0]) +
      (unsigned)(hf * 1024 + (l15 >> 2) * 128 + b4 * 32 + (l15 & 3) * 8);

  int kstart = q0 - 256; if (kstart < 0) kstart = 0;
  int kend = q0 + 384; if (kend > 4096) kend = 4096;

#define STAGE_KV(buf, kb)                                                      \
  do {                                                                         \
    const ushort* Kg = &K[((size_t)hd * 4096 + (kb)) * 64];                    \
    const ushort* Vg = &V[((size_t)hd * 4096 + (kb)) * 64];                    \
    _Pragma("unroll") for (int i = 0; i < 2; i++) {                            \
      int off = i * 2048 + t * 8;                                              \
      int row = off >> 6;                                                      \
      int c8s = (off >> 3) & 7;                                                \
      async_copy16(&lds[buf][0][off], &Kg[row * 64 + ((c8s ^ (row & 7)) * 8)]);\
      async_copy16(&lds[buf][1][off], &Vg[off]);                               \
    }                                                                          \
  } while (0)

  STAGE_KV(0, kstart);
  asm volatile("s_waitcnt vmcnt(0)");
  __builtin_amdgcn_s_barrier();

  for (int kb = kstart; kb < kend; kb += 64) {
    const int cur = ((kb - kstart) >> 6) & 1;
    if (kb + 64 < kend) {
      if (cur) STAGE_KV(0, kb + 64); else STAGE_KV(1, kb + 64);
    }
    bool active = (kb + 63 >= qw - 256) && (kb <= qw + 31 + 256);
    if (active) {
      const ushort* lK = &lds[cur][0][0];
      f32x16 st0 = (f32x16)0.f, st1 = (f32x16)0.f;
      __builtin_amdgcn_s_setprio(1);
#pragma unroll
      for (int kc = 0; kc < 4; kc++) {
        int c8 = 2 * kc + hf;
        int r0 = l31;
        s16x8 kf0 = *(const s16x8*)&lK[r0 * 64 + ((c8 ^ (r0 & 7)) * 8)];
        st0 = __builtin_amdgcn_mfma_f32_32x32x16_bf16(kf0, qf[kc], st0, 0, 0, 0);
        int r1 = 32 + l31;
        s16x8 kf1 = *(const s16x8*)&lK[r1 * 64 + ((c8 ^ (r1 & 7)) * 8)];
        st1 = __builtin_amdgcn_mfma_f32_32x32x16_bf16(kf1, qf[kc], st1, 0, 0, 0);
      }
      __builtin_amdgcn_s_setprio(0);
      const bool interior = (kb >= qw - 225) && (kb <= qw + 193);
      if (!interior) {
        int base0 = myq - kb - 4 * hf + 256;
#pragma unroll
        for (int r = 0; r < 16; r++) {
          int ko = (r & 3) + 8 * (r >> 2);
          if (!((unsigned)(base0 - ko) <= 512u)) st0[r] = -3e38f;
          if (!((unsigned)(base0 - 32 - ko) <= 512u)) st1[r] = -3e38f;
        }
      }
      float rm;
      {
        float a = fmaxf(fmaxf(st0[0], st0[1]), fmaxf(st0[2], st0[3]));
        float b = fmaxf(fmaxf(st0[4], st0[5]), fmaxf(st0[6], st0[7]));
        float c = fmaxf(fmaxf(st0[8], st0[9]), fmaxf(st0[10], st0[11]));
        float d = fmaxf(fmaxf(st0[12], st0[13]), fmaxf(st0[14], st0[15]));
        float e = fmaxf(fmaxf(st1[0], st1[1]), fmaxf(st1[2], st1[3]));
        float f = fmaxf(fmaxf(st1[4], st1[5]), fmaxf(st1[6], st1[7]));
        float g = fmaxf(fmaxf(st1[8], st1[9]), fmaxf(st1[10], st1[11]));
        float h2 = fmaxf(fmaxf(st1[12], st1[13]), fmaxf(st1[14], st1[15]));
        rm = fmaxf(fmaxf(fmaxf(a, b), fmaxf(c, d)), fmaxf(fmaxf(e, f), fmaxf(g, h2)));
      }
      rm = fmaxf(rm, __shfl_xor(rm, 32));
      if (__any(rm > mrow + 8.0f)) {
        float mn = fmaxf(mrow, rm);
        float sc = __builtin_amdgcn_exp2f(mrow - mn);
        mrow = mn;
        int srcB = (lane & 32); srcB += srcB >> 3;
#pragma unroll
        for (int r = 0; r < 16; r++) {
          float scr = __shfl(sc, srcB + (r & 3) + 8 * (r >> 2));
          oa0[r] *= scr; oa1[r] *= scr; oden[r] *= scr;
        }
      }
      // ---- issue ALL 16 tr-reads upfront (outstanding DS == 0 here) ----
      const unsigned vtr = vtr0 + (unsigned)cur * 16384u;
      u32x2 v0, v1, v2, v3, v4, v5, v6, v7, v8, v9, v10, v11, v12, v13, v14, v15;
      TRRD(v0, vtr, 0);     TRRD(v1, vtr, 512);  TRRD(v2, vtr, 64);    TRRD(v3, vtr, 576);
      TRRD(v4, vtr, 2048);  TRRD(v5, vtr, 2560); TRRD(v6, vtr, 2112);  TRRD(v7, vtr, 2624);
      TRRD(v8, vtr, 4096);  TRRD(v9, vtr, 4608); TRRD(v10, vtr, 4160); TRRD(v11, vtr, 4672);
      TRRD(v12, vtr, 6144); TRRD(v13, vtr, 6656); TRRD(v14, vtr, 6208); TRRD(v15, vtr, 6720);
      // ---- pack all P fragments (VALU covers tr-read latency) ----
      U8 pa0, pa1, pa2, pa3;
#define PACK(STV, RB, OUT)                                                     \
  do {                                                                         \
    float e0 = __builtin_amdgcn_exp2f(STV[RB + 0] - mrow);                     \
    float e1 = __builtin_amdgcn_exp2f(STV[RB + 1] - mrow);                     \
    float e2 = __builtin_amdgcn_exp2f(STV[RB + 2] - mrow);                     \
    float e3 = __builtin_amdgcn_exp2f(STV[RB + 3] - mrow);                     \
    float e4 = __builtin_amdgcn_exp2f(STV[RB + 4] - mrow);                     \
    float e5 = __builtin_amdgcn_exp2f(STV[RB + 5] - mrow);                     \
    float e6 = __builtin_amdgcn_exp2f(STV[RB + 6] - mrow);                     \
    float e7 = __builtin_amdgcn_exp2f(STV[RB + 7] - mrow);                     \
    unsigned a0, a1, b0, b1;                                                   \
    asm("v_cvt_pk_bf16_f32 %0, %1, %2" : "=v"(a0) : "v"(e0), "v"(e1));         \
    asm("v_cvt_pk_bf16_f32 %0, %1, %2" : "=v"(a1) : "v"(e2), "v"(e3));         \
    asm("v_cvt_pk_bf16_f32 %0, %1, %2" : "=v"(b0) : "v"(e4), "v"(e5));         \
    asm("v_cvt_pk_bf16_f32 %0, %1, %2" : "=v"(b1) : "v"(e6), "v"(e7));         \
    asm volatile("v_permlane32_swap_b32 %0, %1" : "+v"(a0), "+v"(b0));         \
    asm volatile("v_permlane32_swap_b32 %0, %1" : "+v"(a1), "+v"(b1));         \
    OUT.u[0] = a0; OUT.u[1] = a1; OUT.u[2] = b0; OUT.u[3] = b1;                \
  } while (0)
      PACK(st0, 0, pa0); PACK(st0, 8, pa1); PACK(st1, 0, pa2); PACK(st1, 8, pa3);
#undef PACK
#define MFMA3(PA, VA0, VA1, VB0, VB1)                                          \
  do {                                                                         \
    U8 f0, f1;                                                                 \
    f0.u[0] = VA0[0]; f0.u[1] = VA0[1]; f0.u[2] = VA1[0]; f0.u[3] = VA1[1];    \
    f1.u[0] = VB0[0]; f1.u[1] = VB0[1]; f1.u[2] = VB1[0]; f1.u[3] = VB1[1];    \
    __builtin_amdgcn_s_setprio(1);                                             \
    oa0 = __builtin_amdgcn_mfma_f32_32x32x16_bf16(PA.v, f0.v, oa0, 0, 0, 0);   \
    oa1 = __builtin_amdgcn_mfma_f32_32x32x16_bf16(PA.v, f1.v, oa1, 0, 0, 0);   \
    oden = __builtin_amdgcn_mfma_f32_32x32x16_bf16(PA.v, ones.v, oden, 0, 0, 0);\
    __builtin_amdgcn_s_setprio(0);                                             \
  } while (0)
      asm volatile("s_waitcnt lgkmcnt(12)");
      __builtin_amdgcn_sched_barrier(0);
      MFMA3(pa0, v0, v1, v2, v3);
      asm volatile("s_waitcnt lgkmcnt(8)");
      __builtin_amdgcn_sched_barrier(0);
      MFMA3(pa1, v4, v5, v6, v7);
      asm volatile("s_waitcnt lgkmcnt(4)");
      __builtin_amdgcn_sched_barrier(0);
      MFMA3(pa2, v8, v9, v10, v11);
      asm volatile("s_waitcnt lgkmcnt(0)");
      __builtin_amdgcn_sched_barrier(0);
      MFMA3(pa3, v12, v13, v14, v15);
#undef MFMA3
    }
    asm volatile("s_waitcnt vmcnt(0)");
    __builtin_amdgcn_s_barrier();
  }
#undef STAGE_KV
#pragma unroll
  for (int r = 0; r < 16; r++) {
    float den = __shfl(oden[r], lane & 32);
    float linv = 1.0f / den;
    int s = qw + (r & 3) + 8 * (r >> 2) + 4 * hf;
    out[(size_t)s * 1024 + hd * 64 + l31] = oa0[r] * linv;
    out[(size_t)s * 1024 + hd * 64 + 32 + l31] = oa1[r] * linv;
  }
}

extern "C" void kernel_launch(void* const* d_in, const int* in_sizes, int n_in,
                              void* d_out, int out_size, void* d_ws, size_t ws_size,
                              hipStream_t stream) {
  const float* x  = (const float*)d_in[0];
  const float* Wq = (const float*)d_in[1];
  const float* bq = (const float*)d_in[2];
  const float* Wk = (const float*)d_in[3];
  const float* bk = (const float*)d_in[4];
  const float* Wv = (const float*)d_in[5];
  const float* bv = (const float*)d_in[6];

  ushort* qkv = (ushort*)d_ws;                                   // 24 MB
  ushort* xs  = (ushort*)((char*)d_ws + (size_t)25165824);       // 8 MB
  ushort* wsb = xs + (size_t)4096 * 1024;                        // 6 MB
  float* out = (float*)d_out;

  convert_kernel<<<3584, 256, 0, stream>>>(x, Wq, Wk, Wv, xs, wsb);
  qkv_gemm_kernel<<<256, 512, 0, stream>>>(xs, wsb, bq, bk, bv, qkv);
  attn_local_kernel<<<512, 256, 0, stream>>>(qkv, out);
}